// Round 1
// baseline (352.859 us; speedup 1.0000x reference)
//
#include <hip/hip_runtime.h>
#include <hip/hip_bf16.h>

// Problem constants
#define BSZ 64
#define LL  64
#define SS  63
#define AMB 32
#define HH  128
#define EE  300
#define MLPN 1024
#define GG  640      // 5*H
#define K2  256      // 2*H
#define PP  127      // L+S
#define EPSF 1e-8f

__device__ __forceinline__ float sigf(float x) { return 1.f / (1.f + __expf(-x)); }

// ---------------------------------------------------------------------------
// Prep: transpose W (640x300 -> 300x640), U (640x256 -> 256x640),
//       A (1024x512 -> 512x1024)
// ---------------------------------------------------------------------------
__global__ void prep_kernel(const float* __restrict__ W, const float* __restrict__ U,
                            const float* __restrict__ A,
                            float* __restrict__ WT, float* __restrict__ UT,
                            float* __restrict__ AT) {
    const int n1 = GG * EE;        // 192000
    const int n2 = GG * K2;        // 163840
    const int n3 = MLPN * 512;     // 524288
    int i = blockIdx.x * blockDim.x + threadIdx.x;
    if (i < n1) {
        int k = i / GG, g = i - k * GG;
        WT[i] = W[g * EE + k];
    } else if (i < n1 + n2) {
        int j = i - n1;
        int k = j / GG, g = j - k * GG;
        UT[j] = U[g * K2 + k];
    } else if (i < n1 + n2 + n3) {
        int j = i - n1 - n2;
        int k = j >> 10, c = j & 1023;
        AT[j] = A[c * 512 + k];
    }
}

// ---------------------------------------------------------------------------
// Leaf kernel: 8192 tokens (2 charts x 64 batch x 64 pos), 16 tokens per block.
// preact = emb @ W^T + b ; c = sig(i)*tanh(u); h = sig(o)*tanh(c)
// ---------------------------------------------------------------------------
#define TOKB 16
__global__ void __launch_bounds__(640) leaf_kernel(
        const int* __restrict__ sent1, const int* __restrict__ sent2,
        const float* __restrict__ WT, const float* __restrict__ bias,
        const float* __restrict__ unk, const float* __restrict__ wemb,
        float* __restrict__ chart) {
    __shared__ __align__(16) float lbuf[TOKB * GG];   // 40960 floats, pre overlays emb
    float (*emb)[304] = (float(*)[304])lbuf;          // 16 x 304 (padded)
    float (*pre)[GG]  = (float(*)[GG])lbuf;           // 16 x 640

    const int tid  = threadIdx.x;
    const int tok0 = blockIdx.x * TOKB;

    // Phase 1: load embeddings
    for (int t = 0; t < TOKB; ++t) {
        int tok = tok0 + t;
        int ch  = tok >> 12;
        int idx = tok & 4095;
        int s   = (ch == 0) ? sent1[idx] : sent2[idx];
        const float* src = (s >= 0) ? (wemb + (size_t)s * EE) : unk;
        for (int e = tid; e < EE; e += 640) emb[t][e] = src[e];
        if (tid < 4) emb[t][EE + tid] = 0.f;
    }
    __syncthreads();

    // Phase 2: GEMM — thread g computes preact[g] for all 16 tokens
    const int g = tid;   // 0..639
    float acc[TOKB];
#pragma unroll
    for (int t = 0; t < TOKB; ++t) acc[t] = 0.f;
    for (int k = 0; k < EE; k += 4) {
        float w0 = WT[(k + 0) * GG + g];
        float w1 = WT[(k + 1) * GG + g];
        float w2 = WT[(k + 2) * GG + g];
        float w3 = WT[(k + 3) * GG + g];
#pragma unroll
        for (int t = 0; t < TOKB; ++t) {
            const float4 ev = *(const float4*)&emb[t][k];
            acc[t] = fmaf(w0, ev.x, acc[t]);
            acc[t] = fmaf(w1, ev.y, acc[t]);
            acc[t] = fmaf(w2, ev.z, acc[t]);
            acc[t] = fmaf(w3, ev.w, acc[t]);
        }
    }
    __syncthreads();    // emb no longer needed; pre overlays it
    float bg = bias[g];
#pragma unroll
    for (int t = 0; t < TOKB; ++t) pre[t][g] = acc[t] + bg;
    __syncthreads();

    // Phase 3: gates + chart write
    for (int idx = tid; idx < TOKB * HH; idx += 640) {
        int t = idx >> 7, j = idx & 127;
        float ig = sigf(pre[t][j]);
        float og = sigf(pre[t][3 * HH + j]);
        float ug = tanhf(pre[t][4 * HH + j]);
        float c  = ig * ug;
        float h  = og * tanhf(c);
        int tok = tok0 + t;
        int ch = tok >> 12, rem = tok & 4095;
        int b = rem >> 6, l = rem & 63;
        float* dst = chart + ((size_t)((ch * BSZ + b) * PP + l)) * K2;
        dst[j]      = c;
        dst[HH + j] = h;
    }
}

// ---------------------------------------------------------------------------
// Liveness: backward closure over the step DAG; compact list of live steps.
// ---------------------------------------------------------------------------
__global__ void liveness_kernel(const int* __restrict__ ops1, const int* __restrict__ ops2,
                                const int* __restrict__ oopl1, const int* __restrict__ oopl2,
                                int* __restrict__ live_list, int* __restrict__ nlive_bar) {
    __shared__ unsigned char live[2][64];
    int tid = threadIdx.x;
    if (tid < 128) live[tid >> 6][tid & 63] = 0;
    __syncthreads();
    if (tid < BSZ) {
        int p1 = oopl1[tid] - 1;
        if (p1 >= LL && p1 < PP) live[0][p1 - LL] = 1;
        int p2 = oopl2[tid] - 1;
        if (p2 >= LL && p2 < PP) live[1][p2 - LL] = 1;
    }
    __syncthreads();
    for (int t = SS - 1; t >= 1; --t) {
        if (live[0][t]) {
            for (int i = tid; i < BSZ * 2 * AMB; i += 256) {
                int p = ops1[((i >> 6) * SS + t) * 64 + (i & 63)];
                if (p >= LL && p < PP) live[0][p - LL] = 1;
            }
        }
        if (live[1][t]) {
            for (int i = tid; i < BSZ * 2 * AMB; i += 256) {
                int p = ops2[((i >> 6) * SS + t) * 64 + (i & 63)];
                if (p >= LL && p < PP) live[1][p - LL] = 1;
            }
        }
        __syncthreads();
    }
    if (tid == 0) {
        int n = 0;
        for (int t = 0; t < SS; ++t) {
            int f = (live[0][t] ? 1 : 0) | (live[1][t] ? 2 : 0);
            if (f) live_list[n++] = t | (f << 8);
        }
        nlive_bar[0] = n;
        nlive_bar[1] = 0;   // grid barrier counter
    }
}

// ---------------------------------------------------------------------------
// Step kernel: one block per (chart, batch). Executes live steps in order.
// Grid barrier only between live steps (128 blocks, co-resident).
// ---------------------------------------------------------------------------
__device__ __forceinline__ void gbar(int* bar, int gen) {
    __syncthreads();
    if (threadIdx.x == 0) {
        __threadfence();
        __hip_atomic_fetch_add(bar, 1, __ATOMIC_ACQ_REL, __HIP_MEMORY_SCOPE_AGENT);
        while (__hip_atomic_load(bar, __ATOMIC_ACQUIRE, __HIP_MEMORY_SCOPE_AGENT) < gen * 128) {}
    }
    __syncthreads();
}

__global__ void __launch_bounds__(640) step_kernel(
        const int* __restrict__ ops1, const int* __restrict__ ops2,
        const float* __restrict__ UT, const float* __restrict__ bias,
        const float* __restrict__ eu, const float* __restrict__ invt,
        float* __restrict__ chart,
        const int* __restrict__ live_list, int* __restrict__ nlive_bar) {
    // Shared layout (overlaid):
    //   [0 .. 8191]      hh   (32 x 256)  — GEMM phase
    //   [0 .. 5119]      preq (8 x 640)   — gates phase (per 8-candidate quarter)
    //   [5120 .. 13311]  chs  (32 x 256)  — ccL/ccR then c/h, kept for combine
    __shared__ __align__(16) float sbuf[13312];
    __shared__ float e_num[AMB], h2s[AMB], s_w[AMB];
    __shared__ int ops_lds[64];
    __shared__ float un_sh;

    float* hh   = sbuf;
    float* preq = sbuf;
    float* chs  = sbuf + 5120;

    const int tid = threadIdx.x;
    const int ch  = blockIdx.x >> 6;
    const int b   = blockIdx.x & 63;
    const int* ops = (ch == 0) ? ops1 : ops2;
    const float* chbase = chart + (size_t)(ch * BSZ + b) * PP * K2;
    float* chbase_w = chart + (size_t)(ch * BSZ + b) * PP * K2;
    const float it = invt[0];

    // ||energy_u|| (same for every step)
    if (tid < 64) {
        float v = eu[tid] * eu[tid] + eu[tid + 64] * eu[tid + 64];
        for (int off = 32; off >= 1; off >>= 1) v += __shfl_xor(v, off);
        if (tid == 0) un_sh = fmaxf(sqrtf(v), EPSF);
    }

    const int nl = nlive_bar[0];
    int* bar = nlive_bar + 1;
    int gen = 0;

    for (int sidx = 0; sidx < nl; ++sidx) {
        if (sidx > 0) { ++gen; gbar(bar, gen); }
        int entry = live_list[sidx];
        int t     = entry & 0xff;
        int flags = entry >> 8;
        if (!(flags & (1 << ch))) continue;   // block-uniform

        // Load this step's ops row
        if (tid < 64) {
            int p = ops[(b * SS + t) * 64 + tid];
            ops_lds[tid] = min(max(p, 0), PP - 1);
        }
        __syncthreads();

        // Gather hh = [h_left | h_right] per candidate
        for (int idx = tid; idx < 64 * HH; idx += 640) {
            int j2 = idx >> 7, k = idx & 127;
            int a = j2 >> 1, side = j2 & 1;
            hh[a * K2 + side * HH + k] = chbase[(size_t)ops_lds[j2] * K2 + HH + k];
        }
        __syncthreads();

        // GEMM: thread g holds pre[g] for all 32 candidates
        const int g = tid;
        float acc[AMB];
#pragma unroll
        for (int a = 0; a < AMB; ++a) acc[a] = 0.f;
        for (int k = 0; k < K2; k += 4) {
            float w0 = UT[(k + 0) * GG + g];
            float w1 = UT[(k + 1) * GG + g];
            float w2 = UT[(k + 2) * GG + g];
            float w3 = UT[(k + 3) * GG + g];
#pragma unroll
            for (int a = 0; a < AMB; ++a) {
                const float4 hv = *(const float4*)(hh + a * K2 + k);
                acc[a] = fmaf(w0, hv.x, acc[a]);
                acc[a] = fmaf(w1, hv.y, acc[a]);
                acc[a] = fmaf(w2, hv.z, acc[a]);
                acc[a] = fmaf(w3, hv.w, acc[a]);
            }
        }
        float bg = bias[g];
        __syncthreads();   // hh dead from here

        // Gates + energy, 8 candidates at a time
#pragma unroll
        for (int q = 0; q < 4; ++q) {
            // transpose pre into LDS for this quarter
#pragma unroll
            for (int i = 0; i < 8; ++i) preq[i * GG + g] = acc[q * 8 + i] + bg;
            // gather ccL/ccR for this quarter into chs rows
            for (int idx = tid; idx < 8 * K2; idx += 640) {
                int al = idx >> 8, k = idx & 255;
                int a = q * 8 + al;
                int j2 = 2 * a + (k >> 7);
                chs[a * K2 + k] = chbase[(size_t)ops_lds[j2] * K2 + (k & 127)];
            }
            __syncthreads();
            // gates: c = fL*ccL + fR*ccR + i*u ; h = o*tanh(c)
            for (int idx = tid; idx < 8 * HH; idx += 640) {
                int al = idx >> 7, j = idx & 127;
                int a = q * 8 + al;
                float pi  = preq[al * GG + j];
                float pfl = preq[al * GG + HH + j];
                float pfr = preq[al * GG + 2 * HH + j];
                float po  = preq[al * GG + 3 * HH + j];
                float pu  = preq[al * GG + 4 * HH + j];
                float ccL = chs[a * K2 + j];
                float ccR = chs[a * K2 + HH + j];
                float c = sigf(pfl) * ccL + sigf(pfr) * ccR + sigf(pi) * tanhf(pu);
                float h = sigf(po) * tanhf(c);
                chs[a * K2 + j]      = c;
                chs[a * K2 + HH + j] = h;
            }
            __syncthreads();
            // per-candidate energy numerator and |h|^2 (wave per candidate)
            {
                int wave = tid >> 6, lane = tid & 63;
                if (wave < 8) {
                    int a = q * 8 + wave;
                    float h0 = chs[a * K2 + HH + lane];
                    float h1 = chs[a * K2 + HH + 64 + lane];
                    float pe = h0 * eu[lane] + h1 * eu[64 + lane];
                    float pn = h0 * h0 + h1 * h1;
                    for (int off = 32; off >= 1; off >>= 1) {
                        pe += __shfl_xor(pe, off);
                        pn += __shfl_xor(pn, off);
                    }
                    if (lane == 0) { e_num[a] = pe; h2s[a] = pn; }
                }
            }
            __syncthreads();
        }

        // softmax over 32 candidates (wave 0)
        if (tid < 64) {
            float v = (tid < AMB)
                ? (e_num[tid] / (fmaxf(sqrtf(h2s[tid]), EPSF) * un_sh)) * it
                : -3.4e38f;
            float m = v;
            for (int off = 16; off >= 1; off >>= 1) m = fmaxf(m, __shfl_xor(m, off));
            float ex = (tid < AMB) ? __expf(v - m) : 0.f;
            float sum = ex;
            for (int off = 16; off >= 1; off >>= 1) sum += __shfl_xor(sum, off);
            if (tid < AMB) s_w[tid] = ex / sum;
        }
        __syncthreads();

        // combine: chart[ch][b][L+t][:] = [sum s*c | sum s*h]
        if (tid < K2) {
            float sacc = 0.f;
#pragma unroll
            for (int a = 0; a < AMB; ++a) sacc = fmaf(s_w[a], chs[a * K2 + tid], sacc);
            chbase_w[(size_t)(LL + t) * K2 + tid] = sacc;
        }
        // next iteration begins with gbar (when nl>1), which has __syncthreads
    }
}

// ---------------------------------------------------------------------------
// MLP readout: conc = [(s1-s2)^2, s1*s2, s1, s2]; out = relu(conc @ A^T + a)
// Grid: 16 j-tiles x 4 b-tiles
// ---------------------------------------------------------------------------
__global__ void __launch_bounds__(256) mlp_kernel(
        const float* __restrict__ chart,
        const int* __restrict__ oopl1, const int* __restrict__ oopl2,
        const float* __restrict__ AT, const float* __restrict__ abias,
        float* __restrict__ out) {
    __shared__ __align__(16) float conc[16][512];
    const int tid = threadIdx.x;
    const int jt = blockIdx.x & 15, bt = blockIdx.x >> 4;

    for (int idx = tid; idx < 16 * 512; idx += 256) {
        int bl = idx >> 9, k = idx & 511;
        int b = bt * 16 + bl;
        int kk = k & 127, sel = k >> 7;
        int p1 = min(max(oopl1[b] - 1, 0), PP - 1);
        int p2 = min(max(oopl2[b] - 1, 0), PP - 1);
        float s1 = chart[((size_t)(b * PP + p1)) * K2 + HH + kk];
        float s2 = chart[((size_t)((BSZ + b) * PP + p2)) * K2 + HH + kk];
        float v;
        if (sel == 0)      { float d = s1 - s2; v = d * d; }
        else if (sel == 1) v = s1 * s2;
        else if (sel == 2) v = s1;
        else               v = s2;
        conc[bl][k] = v;
    }
    __syncthreads();

    const int jj = tid & 63, bg = tid >> 6;
    const int j = jt * 64 + jj;
    float aj = abias[j];
    float a0 = aj, a1 = aj, a2 = aj, a3 = aj;
    for (int k = 0; k < 512; ++k) {
        float w = AT[k * MLPN + j];
        a0 = fmaf(w, conc[bg][k],      a0);
        a1 = fmaf(w, conc[bg + 4][k],  a1);
        a2 = fmaf(w, conc[bg + 8][k],  a2);
        a3 = fmaf(w, conc[bg + 12][k], a3);
    }
    out[(size_t)(bt * 16 + bg)      * MLPN + j] = fmaxf(a0, 0.f);
    out[(size_t)(bt * 16 + bg + 4)  * MLPN + j] = fmaxf(a1, 0.f);
    out[(size_t)(bt * 16 + bg + 8)  * MLPN + j] = fmaxf(a2, 0.f);
    out[(size_t)(bt * 16 + bg + 12) * MLPN + j] = fmaxf(a3, 0.f);
}

// ---------------------------------------------------------------------------
extern "C" void kernel_launch(void* const* d_in, const int* in_sizes, int n_in,
                              void* d_out, int out_size, void* d_ws, size_t ws_size,
                              hipStream_t stream) {
    const int*   sent1 = (const int*)d_in[0];
    const int*   ops1  = (const int*)d_in[1];
    const int*   oopl1 = (const int*)d_in[2];
    const int*   sent2 = (const int*)d_in[3];
    const int*   ops2  = (const int*)d_in[4];
    const int*   oopl2 = (const int*)d_in[5];
    const float* W     = (const float*)d_in[6];
    const float* U     = (const float*)d_in[7];
    const float* bias  = (const float*)d_in[8];
    const float* eu    = (const float*)d_in[9];
    const float* unk   = (const float*)d_in[10];
    const float* wemb  = (const float*)d_in[11];
    const float* A     = (const float*)d_in[12];
    const float* ab    = (const float*)d_in[13];
    const float* invt  = (const float*)d_in[14];
    float* out = (float*)d_out;
    (void)in_sizes; (void)n_in; (void)out_size; (void)ws_size;

    char* ws = (char*)d_ws;
    // ws layout (bytes):
    const size_t CHART_OFF = 0;                     // 2*64*127*256*4 = 16,646,144
    const size_t WT_OFF    = 16646144;              // 300*640*4      =    768,000
    const size_t UT_OFF    = 17414144;              // 256*640*4      =    655,360
    const size_t AT_OFF    = 18069504;              // 512*1024*4     =  2,097,152
    const size_t LIST_OFF  = 20166656;              // 64*4
    const size_t NB_OFF    = 20166912;              // nlive + barrier counter
    float* chart     = (float*)(ws + CHART_OFF);
    float* WT        = (float*)(ws + WT_OFF);
    float* UT        = (float*)(ws + UT_OFF);
    float* AT        = (float*)(ws + AT_OFF);
    int*   live_list = (int*)(ws + LIST_OFF);
    int*   nlive_bar = (int*)(ws + NB_OFF);

    // chart must start zeroed (unwritten step rows read as zero; ws is poisoned)
    hipMemsetAsync(chart, 0, (size_t)2 * BSZ * PP * K2 * sizeof(float), stream);

    int prep_n = GG * EE + GG * K2 + MLPN * 512;    // 880128
    prep_kernel<<<(prep_n + 255) / 256, 256, 0, stream>>>(W, U, A, WT, UT, AT);

    leaf_kernel<<<(2 * BSZ * LL) / TOKB, 640, 0, stream>>>(sent1, sent2, WT, bias, unk, wemb, chart);

    liveness_kernel<<<1, 256, 0, stream>>>(ops1, ops2, oopl1, oopl2, live_list, nlive_bar);

    step_kernel<<<2 * BSZ, 640, 0, stream>>>(ops1, ops2, UT, bias, eu, invt, chart,
                                             live_list, nlive_bar);

    mlp_kernel<<<64, 256, 0, stream>>>(chart, oopl1, oopl2, AT, ab, out);
}

// Round 2
// 238.667 us; speedup vs baseline: 1.4785x; 1.4785x over previous
//
#include <hip/hip_runtime.h>
#include <hip/hip_bf16.h>

// Problem constants
#define BSZ 64
#define LL  64
#define SS  63
#define AMB 32
#define HH  128
#define EE  300
#define MLPN 1024
#define GG  640      // 5*H
#define K2  256      // 2*H
#define PP  127      // L+S
#define CSTR 132     // padded LDS row stride (16B-aligned rows, 2-way max bank alias)

typedef __attribute__((ext_vector_type(8))) short short8;   // 8 bf16 (4 VGPRs) MFMA A/B frag
typedef __attribute__((ext_vector_type(4))) float f32x4;    // MFMA C/D frag

__device__ __forceinline__ float sigf(float x) { return 1.f / (1.f + __expf(-x)); }

__device__ __forceinline__ unsigned short f2bf(float x) {
    unsigned int u = __float_as_uint(x);
    u += 0x7fffu + ((u >> 16) & 1u);      // round-to-nearest-even
    return (unsigned short)(u >> 16);
}

// ---------------------------------------------------------------------------
// Prep (fused): bf16 frag-pack W -> WTB, U -> UTB; transpose A -> AT;
// zero chart step-rows; last block runs liveness closure.
//
// Frag-pack layout (B operand of mfma_f32_16x16x32_bf16):
//   XTB[((n*KSTEPS + kk)*64 + lane)*8 + j] = X[g][k],
//   g = n*16 + (lane&15), k = kk*32 + (lane>>4)*8 + j
// ---------------------------------------------------------------------------
#define N1 204800     // WTB shorts: 40 ntiles * 10 ksteps * 512
#define N2 163840     // UTB shorts: 40 * 8 * 512
#define N3 524288     // AT floats
#define N4 516096     // chart zero float4s: 2*64*63 rows * 64
__global__ void __launch_bounds__(256) prep_kernel(
        const float* __restrict__ W, const float* __restrict__ U,
        const float* __restrict__ A,
        const int* __restrict__ ops1, const int* __restrict__ ops2,
        const int* __restrict__ oopl1, const int* __restrict__ oopl2,
        short* __restrict__ WTB, short* __restrict__ UTB,
        float* __restrict__ AT, float* __restrict__ chart,
        int* __restrict__ live_list, int* __restrict__ nlive_bar) {
    __shared__ unsigned char live[2][64];
    const int tid = threadIdx.x;

    if (blockIdx.x == gridDim.x - 1) {
        // ---- liveness closure (single block) ----
        if (tid < 128) live[tid >> 6][tid & 63] = 0;
        __syncthreads();
        if (tid < BSZ) {
            int p1 = oopl1[tid] - 1;
            if (p1 >= LL && p1 < PP) live[0][p1 - LL] = 1;
            int p2 = oopl2[tid] - 1;
            if (p2 >= LL && p2 < PP) live[1][p2 - LL] = 1;
        }
        __syncthreads();
        for (int t = SS - 1; t >= 1; --t) {
            if (live[0][t]) {
                for (int i = tid; i < BSZ * 2 * AMB; i += 256) {
                    int p = ops1[((i >> 6) * SS + t) * 64 + (i & 63)];
                    if (p >= LL && p < PP) live[0][p - LL] = 1;
                }
            }
            if (live[1][t]) {
                for (int i = tid; i < BSZ * 2 * AMB; i += 256) {
                    int p = ops2[((i >> 6) * SS + t) * 64 + (i & 63)];
                    if (p >= LL && p < PP) live[1][p - LL] = 1;
                }
            }
            __syncthreads();
        }
        if (tid == 0) {
            int n = 0;
            for (int t = 0; t < SS; ++t) {
                int f = (live[0][t] ? 1 : 0) | (live[1][t] ? 2 : 0);
                if (f) live_list[n++] = t | (f << 8);
            }
            nlive_bar[0] = n;
            nlive_bar[1] = 0;   // grid barrier counter
        }
        return;
    }

    int idx = blockIdx.x * 256 + tid;
    if (idx < N1) {
        int j = idx & 7, lane = (idx >> 3) & 63, r = idx >> 9;
        int kk = r % 10, n = r / 10;
        int g = n * 16 + (lane & 15);
        int k = kk * 32 + ((lane >> 4) << 3) + j;
        float v = (k < EE) ? W[g * EE + k] : 0.f;
        WTB[idx] = (short)f2bf(v);
    } else if (idx < N1 + N2) {
        int i2 = idx - N1;
        int j = i2 & 7, lane = (i2 >> 3) & 63, r = i2 >> 9;
        int kk = r & 7, n = r >> 3;
        int g = n * 16 + (lane & 15);
        int k = kk * 32 + ((lane >> 4) << 3) + j;
        UTB[i2] = (short)f2bf(U[g * K2 + k]);
    } else if (idx < N1 + N2 + N3) {
        int j3 = idx - N1 - N2;
        int k = j3 >> 10, c = j3 & 1023;
        AT[j3] = A[c * 512 + k];
    } else if (idx < N1 + N2 + N3 + N4) {
        int z = idx - N1 - N2 - N3;
        int rb = z >> 6, off = z & 63;
        int cb = rb / 63, srow = rb - cb * 63;
        float4* p = (float4*)(chart + ((size_t)(cb * PP + LL + srow)) * K2) + off;
        *p = make_float4(0.f, 0.f, 0.f, 0.f);
    }
}

// ---------------------------------------------------------------------------
// Leaf kernel (MFMA): 128 blocks x 256 thr; block = 64 tokens x 640 gates.
// Only gates i,o,u are computed (fL,fR multiply 0 at leaves).
// ---------------------------------------------------------------------------
__global__ void __launch_bounds__(256) leaf_kernel(
        const int* __restrict__ sent1, const int* __restrict__ sent2,
        const short* __restrict__ WTB, const float* __restrict__ bias,
        const float* __restrict__ unk, const float* __restrict__ wemb,
        float* __restrict__ chart) {
    __shared__ short8 As[4 * 10 * 64];   // A-frags: 4 Mtiles x 10 ksteps, 40 KiB
    const int tid  = threadIdx.x;
    const int tok0 = blockIdx.x * 64;
    const int* sent = (tok0 >> 12) ? sent2 : sent1;

    // gather embeddings -> bf16 A-frag layout
    for (int i = 0; i < 10; ++i) {
        int slot = i * 256 + tid;            // 2560 slots = 64 tok x 40 k-octets
        int t = slot / 40, oct = slot % 40;
        int s = sent[(tok0 + t) & 4095];
        const float* src = (s >= 0) ? (wemb + (size_t)s * EE) : unk;
        int k0 = oct * 8;
        float f[8];
        if (k0 + 8 <= EE) {
            f32x4 x0 = *(const f32x4*)(src + k0);
            f32x4 x1 = *(const f32x4*)(src + k0 + 4);
            f[0]=x0[0]; f[1]=x0[1]; f[2]=x0[2]; f[3]=x0[3];
            f[4]=x1[0]; f[5]=x1[1]; f[6]=x1[2]; f[7]=x1[3];
        } else {
#pragma unroll
            for (int j = 0; j < 8; ++j) f[j] = (k0 + j < EE) ? src[k0 + j] : 0.f;
        }
        short8 v;
#pragma unroll
        for (int j = 0; j < 8; ++j) v[j] = (short)f2bf(f[j]);
        As[((t >> 4) * 10 + (oct >> 2)) * 64 + ((oct & 3) << 4) + (t & 15)] = v;
    }
    __syncthreads();

    const int w = tid >> 6, lane = tid & 63;
    const int quad = lane >> 4, l15 = lane & 15;
    for (int cc = 0; cc < 4; ++cc) {
        int chunk = cc * 4 + w;              // 16 chunks = 2 Mgroups x 8 nu
        int mg = chunk >> 3, nu = chunk & 7;
        f32x4 acc[2][3] = {};
        for (int kk = 0; kk < 10; ++kk) {
            short8 a0 = As[((mg * 2 + 0) * 10 + kk) * 64 + lane];
            short8 a1 = As[((mg * 2 + 1) * 10 + kk) * 64 + lane];
#pragma unroll
            for (int si = 0; si < 3; ++si) {
                int s5 = (si == 0) ? 0 : (si == 1 ? 3 : 4);   // gates i, o, u
                int n = nu + 8 * s5;
                short8 b = *(const short8*)(WTB + ((size_t)(n * 10 + kk) * 64 + lane) * 8);
                acc[0][si] = __builtin_amdgcn_mfma_f32_16x16x32_bf16(a0, b, acc[0][si], 0, 0, 0);
                acc[1][si] = __builtin_amdgcn_mfma_f32_16x16x32_bf16(a1, b, acc[1][si], 0, 0, 0);
            }
        }
        int jc = nu * 16 + l15;
        float bi = bias[jc], bo = bias[384 + jc], bu = bias[512 + jc];
#pragma unroll
        for (int mt = 0; mt < 2; ++mt) {
            int tbase = (mg * 2 + mt) * 16 + quad * 4;
#pragma unroll
            for (int r = 0; r < 4; ++r) {
                float pi = acc[mt][0][r] + bi;
                float po = acc[mt][1][r] + bo;
                float pu = acc[mt][2][r] + bu;
                float cv = sigf(pi) * tanhf(pu);
                float hv = sigf(po) * tanhf(cv);
                int tok = tok0 + tbase + r;
                float* dst = chart + ((size_t)(tok >> 6) * PP + (tok & 63)) * K2;
                dst[jc]      = cv;
                dst[HH + jc] = hv;
            }
        }
    }
}

// ---------------------------------------------------------------------------
// Step kernel (MFMA): 128 blocks (chart,batch) x 256 thr, persistent over
// live steps with a grid barrier between steps.
// ---------------------------------------------------------------------------
__device__ __forceinline__ void gbar(int* bar, int gen) {
    __syncthreads();
    if (threadIdx.x == 0) {
        __threadfence();
        __hip_atomic_fetch_add(bar, 1, __ATOMIC_ACQ_REL, __HIP_MEMORY_SCOPE_AGENT);
        while (__hip_atomic_load(bar, __ATOMIC_ACQUIRE, __HIP_MEMORY_SCOPE_AGENT) < gen * 128) {}
    }
    __syncthreads();
}

__global__ void __launch_bounds__(256) step_kernel(
        const int* __restrict__ ops1, const int* __restrict__ ops2,
        const short* __restrict__ UTB, const float* __restrict__ bias,
        const float* __restrict__ eu, const float* __restrict__ invt,
        float* __restrict__ chart,
        const int* __restrict__ live_list, int* __restrict__ nlive_bar) {
    __shared__ short8 As2[2 * 8 * 64];                    // 16 KiB A-frags
    __shared__ __align__(16) float ccL[AMB][CSTR], ccR[AMB][CSTR];
    __shared__ __align__(16) float chc[AMB][CSTR], chh[AMB][CSTR];
    __shared__ float e_num[AMB], h2s[AMB], s_w[AMB];
    __shared__ int ops_lds[64];
    __shared__ float un_sh;

    const int tid = threadIdx.x;
    const int ch = blockIdx.x >> 6, b = blockIdx.x & 63;
    const int* ops = ch ? ops2 : ops1;
    float* chbase = chart + (size_t)(ch * BSZ + b) * PP * K2;
    const float it = invt[0];
    const int w = tid >> 6, lane = tid & 63, quad = lane >> 4, l15 = lane & 15;

    if (tid < 64) {
        float v = eu[tid] * eu[tid] + eu[tid + 64] * eu[tid + 64];
        for (int off = 32; off >= 1; off >>= 1) v += __shfl_xor(v, off);
        if (tid == 0) un_sh = fmaxf(sqrtf(v), 1e-8f);
    }
    const float eul = eu[lane], euh = eu[64 + lane];
    const int nl = nlive_bar[0];
    int* bar = nlive_bar + 1;

    for (int sidx = 0; sidx < nl; ++sidx) {
        if (sidx > 0) gbar(bar, sidx);
        int entry = live_list[sidx];
        int t = entry & 0xff, flags = entry >> 8;
        if (!(flags & (1 << ch))) continue;      // block-uniform

        if (tid < 64) ops_lds[tid] = min(max(ops[(b * SS + t) * 64 + tid], 0), PP - 1);
        __syncthreads();

        // gather: h -> bf16 A-frags, c -> fp32 LDS
        for (int i = 0; i < 4; ++i) {
            int slot = i * 256 + tid;            // 1024 = 32 cand x 32 octets
            int a = slot >> 5, oct = slot & 31;
            int side = oct >> 4, m8 = oct & 15;
            const float* src = chbase + (size_t)ops_lds[2 * a + side] * K2;
            const float* sh = src + HH + m8 * 8;
            f32x4 x0 = *(const f32x4*)sh;
            f32x4 x1 = *(const f32x4*)(sh + 4);
            short8 v;
            v[0]=(short)f2bf(x0[0]); v[1]=(short)f2bf(x0[1]); v[2]=(short)f2bf(x0[2]); v[3]=(short)f2bf(x0[3]);
            v[4]=(short)f2bf(x1[0]); v[5]=(short)f2bf(x1[1]); v[6]=(short)f2bf(x1[2]); v[7]=(short)f2bf(x1[3]);
            As2[((a >> 4) * 8 + (oct >> 2)) * 64 + ((oct & 3) << 4) + (a & 15)] = v;
            const float* sc = src + m8 * 8;
            float* dst = (side ? ccR[a] : ccL[a]) + m8 * 8;
            *(f32x4*)dst       = *(const f32x4*)sc;
            *(f32x4*)(dst + 4) = *(const f32x4*)(sc + 4);
        }
        __syncthreads();

        // GEMM (2 nu-chunks per wave) + in-register gates
        for (int cc2 = 0; cc2 < 2; ++cc2) {
            int nu = cc2 * 4 + w;
            f32x4 acc[2][5] = {};
            for (int kk = 0; kk < 8; ++kk) {
                short8 a0 = As2[(0 * 8 + kk) * 64 + lane];
                short8 a1 = As2[(1 * 8 + kk) * 64 + lane];
#pragma unroll
                for (int s5 = 0; s5 < 5; ++s5) {
                    int n = nu + 8 * s5;
                    short8 bb = *(const short8*)(UTB + ((size_t)(n * 8 + kk) * 64 + lane) * 8);
                    acc[0][s5] = __builtin_amdgcn_mfma_f32_16x16x32_bf16(a0, bb, acc[0][s5], 0, 0, 0);
                    acc[1][s5] = __builtin_amdgcn_mfma_f32_16x16x32_bf16(a1, bb, acc[1][s5], 0, 0, 0);
                }
            }
            int jc = nu * 16 + l15;
            float bi = bias[jc], bfl = bias[HH + jc], bfr = bias[2 * HH + jc];
            float bo = bias[3 * HH + jc], bu = bias[4 * HH + jc];
#pragma unroll
            for (int mt = 0; mt < 2; ++mt)
#pragma unroll
            for (int r = 0; r < 4; ++r) {
                int a = mt * 16 + quad * 4 + r;
                float pi  = acc[mt][0][r] + bi;
                float pfl = acc[mt][1][r] + bfl;
                float pfr = acc[mt][2][r] + bfr;
                float po  = acc[mt][3][r] + bo;
                float pu  = acc[mt][4][r] + bu;
                float cv = sigf(pfl) * ccL[a][jc] + sigf(pfr) * ccR[a][jc] + sigf(pi) * tanhf(pu);
                float hv = sigf(po) * tanhf(cv);
                chc[a][jc] = cv;
                chh[a][jc] = hv;
            }
        }
        __syncthreads();

        // energy per candidate (each wave: 8 candidates)
        for (int ii = 0; ii < 8; ++ii) {
            int a = w * 8 + ii;
            float h0 = chh[a][lane], h1 = chh[a][64 + lane];
            float pe = h0 * eul + h1 * euh;
            float pn = h0 * h0 + h1 * h1;
            for (int off = 32; off >= 1; off >>= 1) {
                pe += __shfl_xor(pe, off);
                pn += __shfl_xor(pn, off);
            }
            if (lane == 0) { e_num[a] = pe; h2s[a] = pn; }
        }
        __syncthreads();

        // softmax over 32 candidates
        if (tid < 64) {
            float v = (tid < AMB)
                ? (e_num[tid] / (fmaxf(sqrtf(h2s[tid]), 1e-8f) * un_sh)) * it
                : -3.4e38f;
            float m = v;
            for (int off = 16; off >= 1; off >>= 1) m = fmaxf(m, __shfl_xor(m, off));
            float ex = (tid < AMB) ? __expf(v - m) : 0.f;
            float su = ex;
            for (int off = 16; off >= 1; off >>= 1) su += __shfl_xor(su, off);
            if (tid < AMB) s_w[tid] = ex / su;
        }
        __syncthreads();

        // combine and write chart row L+t
        {
            float sacc = 0.f;
            if (tid < HH) {
#pragma unroll
                for (int a = 0; a < AMB; ++a) sacc = fmaf(s_w[a], chc[a][tid], sacc);
            } else {
#pragma unroll
                for (int a = 0; a < AMB; ++a) sacc = fmaf(s_w[a], chh[a][tid - HH], sacc);
            }
            chbase[(size_t)(LL + t) * K2 + tid] = sacc;
        }
        __syncthreads();
    }
}

// ---------------------------------------------------------------------------
// MLP readout (fp32, vectorized inner loop)
// ---------------------------------------------------------------------------
__global__ void __launch_bounds__(256) mlp_kernel(
        const float* __restrict__ chart,
        const int* __restrict__ oopl1, const int* __restrict__ oopl2,
        const float* __restrict__ AT, const float* __restrict__ abias,
        float* __restrict__ out) {
    __shared__ __align__(16) float conc[16][512];
    const int tid = threadIdx.x;
    const int jt = blockIdx.x & 15, bt = blockIdx.x >> 4;

    for (int idx = tid; idx < 16 * 512; idx += 256) {
        int bl = idx >> 9, k = idx & 511;
        int b = bt * 16 + bl;
        int kk = k & 127, sel = k >> 7;
        int p1 = min(max(oopl1[b] - 1, 0), PP - 1);
        int p2 = min(max(oopl2[b] - 1, 0), PP - 1);
        float s1 = chart[((size_t)(b * PP + p1)) * K2 + HH + kk];
        float s2 = chart[((size_t)((BSZ + b) * PP + p2)) * K2 + HH + kk];
        float v;
        if (sel == 0)      { float d = s1 - s2; v = d * d; }
        else if (sel == 1) v = s1 * s2;
        else if (sel == 2) v = s1;
        else               v = s2;
        conc[bl][k] = v;
    }
    __syncthreads();

    const int jj = tid & 63, bg = tid >> 6;
    const int j = jt * 64 + jj;
    float aj = abias[j];
    float a0 = aj, a1 = aj, a2 = aj, a3 = aj;
    for (int k = 0; k < 512; k += 4) {
        f32x4 c0 = *(const f32x4*)&conc[bg][k];
        f32x4 c1 = *(const f32x4*)&conc[bg + 4][k];
        f32x4 c2 = *(const f32x4*)&conc[bg + 8][k];
        f32x4 c3 = *(const f32x4*)&conc[bg + 12][k];
#pragma unroll
        for (int u = 0; u < 4; ++u) {
            float wv = AT[(size_t)(k + u) * MLPN + j];
            a0 = fmaf(wv, c0[u], a0);
            a1 = fmaf(wv, c1[u], a1);
            a2 = fmaf(wv, c2[u], a2);
            a3 = fmaf(wv, c3[u], a3);
        }
    }
    out[(size_t)(bt * 16 + bg)      * MLPN + j] = fmaxf(a0, 0.f);
    out[(size_t)(bt * 16 + bg + 4)  * MLPN + j] = fmaxf(a1, 0.f);
    out[(size_t)(bt * 16 + bg + 8)  * MLPN + j] = fmaxf(a2, 0.f);
    out[(size_t)(bt * 16 + bg + 12) * MLPN + j] = fmaxf(a3, 0.f);
}

// ---------------------------------------------------------------------------
extern "C" void kernel_launch(void* const* d_in, const int* in_sizes, int n_in,
                              void* d_out, int out_size, void* d_ws, size_t ws_size,
                              hipStream_t stream) {
    const int*   sent1 = (const int*)d_in[0];
    const int*   ops1  = (const int*)d_in[1];
    const int*   oopl1 = (const int*)d_in[2];
    const int*   sent2 = (const int*)d_in[3];
    const int*   ops2  = (const int*)d_in[4];
    const int*   oopl2 = (const int*)d_in[5];
    const float* W     = (const float*)d_in[6];
    const float* U     = (const float*)d_in[7];
    const float* bias  = (const float*)d_in[8];
    const float* eu    = (const float*)d_in[9];
    const float* unk   = (const float*)d_in[10];
    const float* wemb  = (const float*)d_in[11];
    const float* A     = (const float*)d_in[12];
    const float* ab    = (const float*)d_in[13];
    const float* invt  = (const float*)d_in[14];
    float* out = (float*)d_out;
    (void)in_sizes; (void)n_in; (void)out_size; (void)ws_size;

    char* ws = (char*)d_ws;
    // ws layout (bytes):
    const size_t CHART_OFF = 0;                  // 2*64*127*256*4 = 16,646,144
    const size_t WTB_OFF   = 16646144;           // 204800*2       =    409,600
    const size_t UTB_OFF   = 17055744;           // 163840*2       =    327,680
    const size_t AT_OFF    = 17383424;           // 524288*4       =  2,097,152
    const size_t LIST_OFF  = 19480576;           // 64*4
    const size_t NB_OFF    = 19480832;           // nlive + barrier counter
    float* chart     = (float*)(ws + CHART_OFF);
    short* WTB       = (short*)(ws + WTB_OFF);
    short* UTB       = (short*)(ws + UTB_OFF);
    float* AT        = (float*)(ws + AT_OFF);
    int*   live_list = (int*)(ws + LIST_OFF);
    int*   nlive_bar = (int*)(ws + NB_OFF);

    // prep grid: (N1+N2+N3+N4)/256 = 5504 work blocks + 1 liveness block
    prep_kernel<<<5505, 256, 0, stream>>>(W, U, A, ops1, ops2, oopl1, oopl2,
                                          WTB, UTB, AT, chart, live_list, nlive_bar);

    leaf_kernel<<<128, 256, 0, stream>>>(sent1, sent2, WTB, bias, unk, wemb, chart);

    step_kernel<<<128, 256, 0, stream>>>(ops1, ops2, UTB, bias, eu, invt, chart,
                                         live_list, nlive_bar);

    mlp_kernel<<<64, 256, 0, stream>>>(chart, oopl1, oopl2, AT, ab, out);
}

// Round 3
// 214.047 us; speedup vs baseline: 1.6485x; 1.1150x over previous
//
#include <hip/hip_runtime.h>
#include <hip/hip_bf16.h>

// Problem constants
#define BSZ 64
#define LL  64
#define SS  63
#define AMB 32
#define HH  128
#define EE  300
#define MLPN 1024
#define GG  640      // 5*H
#define K2  256      // 2*H
#define PP  127      // L+S
#define CCS 36       // LDS row stride for 32-col slices: 4*36 % 32 == 16 -> quad halves disjoint

typedef __attribute__((ext_vector_type(8))) short short8;   // 8 bf16 MFMA A/B frag
typedef __attribute__((ext_vector_type(4))) float f32x4;

__device__ __forceinline__ float sigf(float x) { return 1.f / (1.f + __expf(-x)); }

__device__ __forceinline__ unsigned short f2bf(float x) {
    unsigned int u = __float_as_uint(x);
    u += 0x7fffu + ((u >> 16) & 1u);      // RNE
    return (unsigned short)(u >> 16);
}

// ---------------------------------------------------------------------------
// Prep: frag-pack W->WTB (bf16), U->UTB (bf16); zero chart step rows;
// last block runs the liveness closure.
// Frag layout (B operand, mfma_f32_16x16x32_bf16):
//   XTB[((n*KSTEPS + kk)*64 + lane)*8 + j] = X[g][k],
//   g = n*16 + (lane&15), k = kk*32 + (lane>>4)*8 + j
// ---------------------------------------------------------------------------
#define PW 25600     // WTB short8 items: 40 ntiles * 10 ksteps * 64 lanes
#define PU 20480     // UTB short8 items: 40 * 8 * 64
#define PZ 129024    // zero items (64 B each): 2*64*63 rows * 256 floats / 16
__global__ void __launch_bounds__(256) prep_kernel(
        const float* __restrict__ W, const float* __restrict__ U,
        const int* __restrict__ ops1, const int* __restrict__ ops2,
        const int* __restrict__ oopl1, const int* __restrict__ oopl2,
        short* __restrict__ WTB, short* __restrict__ UTB,
        float* __restrict__ chart,
        int* __restrict__ live_list, int* __restrict__ nlive_bar) {
    __shared__ unsigned char live[2][64];
    const int tid = threadIdx.x;

    if (blockIdx.x == gridDim.x - 1) {
        // ---- liveness closure (single block) ----
        if (tid < 128) live[tid >> 6][tid & 63] = 0;
        __syncthreads();
        if (tid < BSZ) {
            int p1 = oopl1[tid] - 1;
            if (p1 >= LL && p1 < PP) live[0][p1 - LL] = 1;
            int p2 = oopl2[tid] - 1;
            if (p2 >= LL && p2 < PP) live[1][p2 - LL] = 1;
        }
        __syncthreads();
        for (int t = SS - 1; t >= 1; --t) {
            if (live[0][t]) {
                for (int i = tid; i < BSZ * 2 * AMB; i += 256) {
                    int p = ops1[((i >> 6) * SS + t) * 64 + (i & 63)];
                    if (p >= LL && p < PP) live[0][p - LL] = 1;
                }
            }
            if (live[1][t]) {
                for (int i = tid; i < BSZ * 2 * AMB; i += 256) {
                    int p = ops2[((i >> 6) * SS + t) * 64 + (i & 63)];
                    if (p >= LL && p < PP) live[1][p - LL] = 1;
                }
            }
            __syncthreads();
        }
        if (tid == 0) {
            int n = 0;
            for (int t = 0; t < SS; ++t) {
                int f = (live[0][t] ? 1 : 0) | (live[1][t] ? 2 : 0);
                if (f) live_list[n++] = t | (f << 8);
            }
            nlive_bar[0] = n;
            nlive_bar[1] = 0;   // grid barrier counter
        }
        return;
    }

    int idx = blockIdx.x * 256 + tid;
    if (idx < PW) {
        int lane = idx & 63, r = idx >> 6;
        int kk = r % 10, n = r / 10;
        int g = n * 16 + (lane & 15);
        int k0 = kk * 32 + ((lane >> 4) << 3);
        const float* src = W + (size_t)g * EE + k0;
        float f[8];
        if (k0 + 8 <= EE) {
            f32x4 x0 = *(const f32x4*)src;
            f32x4 x1 = *(const f32x4*)(src + 4);
            f[0]=x0[0]; f[1]=x0[1]; f[2]=x0[2]; f[3]=x0[3];
            f[4]=x1[0]; f[5]=x1[1]; f[6]=x1[2]; f[7]=x1[3];
        } else {
#pragma unroll
            for (int j = 0; j < 8; ++j) f[j] = (k0 + j < EE) ? src[j] : 0.f;
        }
        short8 v;
#pragma unroll
        for (int j = 0; j < 8; ++j) v[j] = (short)f2bf(f[j]);
        *(short8*)(WTB + (size_t)idx * 8) = v;
    } else if (idx < PW + PU) {
        int o = idx - PW;
        int lane = o & 63, r = o >> 6;
        int kk = r & 7, n = r >> 3;
        int g = n * 16 + (lane & 15);
        int k0 = kk * 32 + ((lane >> 4) << 3);
        const float* src = U + (size_t)g * K2 + k0;
        f32x4 x0 = *(const f32x4*)src;
        f32x4 x1 = *(const f32x4*)(src + 4);
        short8 v;
        v[0]=(short)f2bf(x0[0]); v[1]=(short)f2bf(x0[1]); v[2]=(short)f2bf(x0[2]); v[3]=(short)f2bf(x0[3]);
        v[4]=(short)f2bf(x1[0]); v[5]=(short)f2bf(x1[1]); v[6]=(short)f2bf(x1[2]); v[7]=(short)f2bf(x1[3]);
        *(short8*)(UTB + (size_t)o * 8) = v;
    } else if (idx < PW + PU + PZ) {
        int z = idx - PW - PU;
        int row = z >> 4;                 // 16 z-items per 256-float row
        int pair = row / 63, srow = row - pair * 63;
        float* p = chart + ((size_t)pair * PP + LL + srow) * K2 + ((z & 15) << 4);
        f32x4 zero = {0.f, 0.f, 0.f, 0.f};
        *(f32x4*)p = zero; *(f32x4*)(p+4) = zero; *(f32x4*)(p+8) = zero; *(f32x4*)(p+12) = zero;
    }
}

// ---------------------------------------------------------------------------
// Leaf (MFMA): 256 blocks x 256 thr; block = 32 tokens x 640 gates.
// Gates i,o,u only (fL,fR multiply 0 at leaves).
// ---------------------------------------------------------------------------
__global__ void __launch_bounds__(256) leaf_kernel(
        const int* __restrict__ sent1, const int* __restrict__ sent2,
        const short* __restrict__ WTB, const float* __restrict__ bias,
        const float* __restrict__ unk, const float* __restrict__ wemb,
        float* __restrict__ chart) {
    __shared__ short8 As[2 * 10 * 64];   // 20 KiB A-frags (2 Mtiles x 10 ksteps)
    const int tid  = threadIdx.x;
    const int tok0 = blockIdx.x * 32;
    const int* sent = (blockIdx.x >= 128) ? sent2 : sent1;

    // register-staged gather (all 10 vec4 loads in flight before packing)
    float f[5][8];
    int ts[5], os[5];
#pragma unroll
    for (int i = 0; i < 5; ++i) {
        int slot = i * 256 + tid;             // 1280 = 32 tok x 40 k-octets
        int t = slot / 40, oct = slot - t * 40;
        ts[i] = t; os[i] = oct;
        int s = sent[(tok0 + t) & 4095];
        const float* src = (s >= 0) ? (wemb + (size_t)s * EE) : unk;
        int k0 = oct * 8;
        if (k0 + 8 <= EE) {
            f32x4 x0 = *(const f32x4*)(src + k0);
            f32x4 x1 = *(const f32x4*)(src + k0 + 4);
            f[i][0]=x0[0]; f[i][1]=x0[1]; f[i][2]=x0[2]; f[i][3]=x0[3];
            f[i][4]=x1[0]; f[i][5]=x1[1]; f[i][6]=x1[2]; f[i][7]=x1[3];
        } else {
#pragma unroll
            for (int j = 0; j < 8; ++j) f[i][j] = (k0 + j < EE) ? src[k0 + j] : 0.f;
        }
    }
#pragma unroll
    for (int i = 0; i < 5; ++i) {
        int t = ts[i], oct = os[i];
        short8 v;
#pragma unroll
        for (int j = 0; j < 8; ++j) v[j] = (short)f2bf(f[i][j]);
        As[((t >> 4) * 10 + (oct >> 2)) * 64 + ((oct & 3) << 4) + (t & 15)] = v;
    }
    __syncthreads();

    const int w = tid >> 6, lane = tid & 63;
    const int quad = lane >> 4, l15 = lane & 15;
    for (int cc = 0; cc < 2; ++cc) {
        int nu = cc * 4 + w;
        f32x4 acc[2][3] = {};
        for (int kk = 0; kk < 10; ++kk) {
            short8 a0 = As[kk * 64 + lane];
            short8 a1 = As[(10 + kk) * 64 + lane];
#pragma unroll
            for (int si = 0; si < 3; ++si) {
                int s5 = (si == 0) ? 0 : (si == 1 ? 3 : 4);   // gates i,o,u
                short8 bv = *(const short8*)(WTB + ((size_t)((nu + 8 * s5) * 10 + kk) * 64 + lane) * 8);
                acc[0][si] = __builtin_amdgcn_mfma_f32_16x16x32_bf16(a0, bv, acc[0][si], 0, 0, 0);
                acc[1][si] = __builtin_amdgcn_mfma_f32_16x16x32_bf16(a1, bv, acc[1][si], 0, 0, 0);
            }
        }
        int jc = nu * 16 + l15;
        float bi = bias[jc], bo = bias[384 + jc], bu = bias[512 + jc];
#pragma unroll
        for (int mt = 0; mt < 2; ++mt)
#pragma unroll
        for (int r = 0; r < 4; ++r) {
            float pi = acc[mt][0][r] + bi;
            float po = acc[mt][1][r] + bo;
            float pu = acc[mt][2][r] + bu;
            float cv = sigf(pi) * tanhf(pu);
            float hv = sigf(po) * tanhf(cv);
            int tok = tok0 + mt * 16 + quad * 4 + r;
            float* dst = chart + ((size_t)(tok >> 6) * PP + (tok & 63)) * K2;
            dst[jc]      = cv;
            dst[HH + jc] = hv;
        }
    }
}

// ---------------------------------------------------------------------------
// Step (MFMA, persistent): 512 blocks = 128 (chart,batch) pairs x 4 N-slices.
// Cross-slice energy reduction via per-slice scratch + grid barrier.
// ---------------------------------------------------------------------------
#define GRID_STEP 512
__device__ __forceinline__ void gbar(int* bar, int gen) {
    __syncthreads();
    if (threadIdx.x == 0) {
        __threadfence();
        __hip_atomic_fetch_add(bar, 1, __ATOMIC_ACQ_REL, __HIP_MEMORY_SCOPE_AGENT);
        while (__hip_atomic_load(bar, __ATOMIC_ACQUIRE, __HIP_MEMORY_SCOPE_AGENT) < gen * GRID_STEP)
            __builtin_amdgcn_s_sleep(2);
        __threadfence();
    }
    __syncthreads();
}

__global__ void __launch_bounds__(256, 2) step_kernel(
        const int* __restrict__ ops1, const int* __restrict__ ops2,
        const short* __restrict__ UTB, const float* __restrict__ bias,
        const float* __restrict__ eu, const float* __restrict__ invt,
        float* __restrict__ chart,
        const int* __restrict__ live_list, int* __restrict__ nlive_bar,
        float* __restrict__ e_scr) {
    // LDS: As2 16 KiB | ccL/ccR/chc/chh 4x[32][36] f32 (4.5 KiB each)
    __shared__ __align__(16) char smem[16384 + 4 * (32 * CCS * 4)];
    short8* As2 = (short8*)smem;
    float* ccL = (float*)(smem + 16384);
    float* ccR = (float*)(smem + 16384 + 4608);
    float* chc = (float*)(smem + 16384 + 2 * 4608);
    float* chh = (float*)(smem + 16384 + 3 * 4608);
    __shared__ int ops_lds[64];
    __shared__ float s_w[AMB];
    __shared__ float un_sh;

    const int tid = threadIdx.x;
    const int pair = blockIdx.x >> 2, slice = blockIdx.x & 3;
    const int ch = pair >> 6, b = pair & 63;
    const int* ops = ch ? ops2 : ops1;
    float* chbase = chart + (size_t)pair * PP * K2;
    const float it = invt[0];
    const int w = tid >> 6, lane = tid & 63, quad = lane >> 4, l15 = lane & 15;
    const int mt = w >> 1, nul = w & 1, nu = slice * 2 + nul;
    const int jc = nu * 16 + l15, lc = nul * 16 + l15;
    const float bi  = bias[jc],          bfl = bias[HH + jc];
    const float bfr = bias[2 * HH + jc], bo  = bias[3 * HH + jc];
    const float bu  = bias[4 * HH + jc];
    const float euc = eu[slice * 32 + (lane & 31)];   // energy column weight

    if (tid < 64) {
        float v = eu[tid] * eu[tid] + eu[tid + 64] * eu[tid + 64];
        for (int off = 32; off >= 1; off >>= 1) v += __shfl_xor(v, off);
        if (tid == 0) un_sh = fmaxf(sqrtf(v), 1e-8f);
    }
    __syncthreads();

    const int nl = nlive_bar[0];
    int* bar = nlive_bar + 1;
    int gen = 0;

    for (int sidx = 0; sidx < nl; ++sidx) {
        int entry = live_list[sidx];
        int t = entry & 0xff;
        bool active = (entry >> (8 + ch)) & 1;

        if (active) {
            // ---- head: gather + GEMM + gates + energy partials ----
            if (tid < 64) ops_lds[tid] = min(max(ops[(b * SS + t) * 64 + tid], 0), PP - 1);
            __syncthreads();

            float hf[4][8];
            int ha[4], ho[4];
#pragma unroll
            for (int i = 0; i < 4; ++i) {
                int s = i * 256 + tid;            // 1024 = 32 cand x 32 h-octets
                int a = s >> 5, oct = s & 31, side = oct >> 4, m8 = oct & 15;
                ha[i] = a; ho[i] = oct;
                const float* src = chbase + (size_t)ops_lds[2 * a + side] * K2 + HH + m8 * 8;
                f32x4 x0 = *(const f32x4*)src;
                f32x4 x1 = *(const f32x4*)(src + 4);
                hf[i][0]=x0[0]; hf[i][1]=x0[1]; hf[i][2]=x0[2]; hf[i][3]=x0[3];
                hf[i][4]=x1[0]; hf[i][5]=x1[1]; hf[i][6]=x1[2]; hf[i][7]=x1[3];
            }
            f32x4 cv4[2];
            int ca[2], cq[2], cs[2];
#pragma unroll
            for (int i = 0; i < 2; ++i) {
                int s2 = i * 256 + tid;           // 512 = 32 cand x 2 sides x 8 vec4
                int a = s2 >> 4, rest = s2 & 15, side = rest >> 3, qi = rest & 7;
                ca[i] = a; cq[i] = qi; cs[i] = side;
                cv4[i] = *(const f32x4*)(chbase + (size_t)ops_lds[2 * a + side] * K2 + slice * 32 + qi * 4);
            }
#pragma unroll
            for (int i = 0; i < 4; ++i) {
                short8 v;
#pragma unroll
                for (int j = 0; j < 8; ++j) v[j] = (short)f2bf(hf[i][j]);
                As2[((ha[i] >> 4) * 8 + (ho[i] >> 2)) * 64 + ((ho[i] & 3) << 4) + (ha[i] & 15)] = v;
            }
#pragma unroll
            for (int i = 0; i < 2; ++i) {
                float* dst = (cs[i] ? ccR : ccL) + ca[i] * CCS + cq[i] * 4;
                *(f32x4*)dst = cv4[i];
            }
            __syncthreads();

            f32x4 acc[5] = {};
            for (int kk = 0; kk < 8; ++kk) {
                short8 a0 = As2[(mt * 8 + kk) * 64 + lane];
#pragma unroll
                for (int s5 = 0; s5 < 5; ++s5) {
                    short8 bb = *(const short8*)(UTB + ((size_t)((nu + 8 * s5) * 8 + kk) * 64 + lane) * 8);
                    acc[s5] = __builtin_amdgcn_mfma_f32_16x16x32_bf16(a0, bb, acc[s5], 0, 0, 0);
                }
            }
#pragma unroll
            for (int r = 0; r < 4; ++r) {
                int a = mt * 16 + quad * 4 + r;
                float cv = sigf(acc[1][r] + bfl) * ccL[a * CCS + lc]
                         + sigf(acc[2][r] + bfr) * ccR[a * CCS + lc]
                         + sigf(acc[0][r] + bi) * tanhf(acc[4][r] + bu);
                float hv = sigf(acc[3][r] + bo) * tanhf(cv);
                chc[a * CCS + lc] = cv;
                chh[a * CCS + lc] = hv;
            }
            __syncthreads();

            // energy partials over this slice's 32 columns (2 cands / iter / wave)
#pragma unroll
            for (int ii = 0; ii < 4; ++ii) {
                int a = w * 8 + ii * 2 + (lane >> 5);
                float hv = chh[a * CCS + (lane & 31)];
                float pe = hv * euc, pn = hv * hv;
                for (int off = 16; off >= 1; off >>= 1) {
                    pe += __shfl_xor(pe, off);
                    pn += __shfl_xor(pn, off);
                }
                if ((lane & 31) == 0) {
                    float* d = e_scr + ((size_t)(pair * 4 + slice) * 32 + a) * 2;
                    d[0] = pe; d[1] = pn;
                }
            }
        }

        ++gen; gbar(bar, gen);   // all 512 blocks, unconditional

        if (active) {
            // ---- tail: softmax + combine ----
            if (tid < 32) {
                const float* es = e_scr + (size_t)pair * 256 + tid * 2;
                float num = es[0] + es[64] + es[128] + es[192];
                float h2  = es[1] + es[65] + es[129] + es[193];
                float v = (num / (fmaxf(sqrtf(h2), 1e-8f) * un_sh)) * it;
                float m = v;
                for (int off = 16; off >= 1; off >>= 1) m = fmaxf(m, __shfl_xor(m, off));
                float ex = __expf(v - m);
                float su = ex;
                for (int off = 16; off >= 1; off >>= 1) su += __shfl_xor(su, off);
                s_w[tid] = ex / su;
            }
            __syncthreads();
            if (tid < 64) {
                int half = tid >> 5, lcc = tid & 31;
                const float* srcA = half ? chh : chc;
                float sacc = 0.f;
#pragma unroll
                for (int a = 0; a < AMB; ++a) sacc = fmaf(s_w[a], srcA[a * CCS + lcc], sacc);
                chbase[(size_t)(LL + t) * K2 + half * HH + slice * 32 + lcc] = sacc;
            }
            __syncthreads();
        }

        if (sidx + 1 < nl) { ++gen; gbar(bar, gen); }  // chart row visible before next gather
    }
}

// ---------------------------------------------------------------------------
// MLP readout: 256 blocks = 16 j-tiles x 16 b-tiles (4 batch rows each).
// A read row-major directly (L1 line reuse over 16-k windows).
// ---------------------------------------------------------------------------
__global__ void __launch_bounds__(256) mlp_kernel(
        const float* __restrict__ chart,
        const int* __restrict__ oopl1, const int* __restrict__ oopl2,
        const float* __restrict__ A, const float* __restrict__ abias,
        float* __restrict__ out) {
    __shared__ __align__(16) float conc[4][512];
    const int tid = threadIdx.x;
    const int jt = blockIdx.x & 15, bt = blockIdx.x >> 4;

#pragma unroll
    for (int i = 0; i < 2; ++i) {
        int s = i * 256 + tid;                // 512 vec4 slots = 4 b x 128
        int bl = s >> 7, kv = s & 127;
        int k0 = kv * 4, sel = k0 >> 7, kk0 = k0 & 127;
        int b = bt * 4 + bl;
        int p1 = min(max(oopl1[b] - 1, 0), PP - 1);
        int p2 = min(max(oopl2[b] - 1, 0), PP - 1);
        f32x4 s1 = *(const f32x4*)(chart + ((size_t)(b * PP + p1)) * K2 + HH + kk0);
        f32x4 s2 = *(const f32x4*)(chart + ((size_t)((BSZ + b) * PP + p2)) * K2 + HH + kk0);
        f32x4 v;
        if (sel == 0)      { f32x4 d = s1 - s2; v = d * d; }
        else if (sel == 1) v = s1 * s2;
        else if (sel == 2) v = s1;
        else               v = s2;
        *(f32x4*)&conc[bl][k0] = v;
    }
    __syncthreads();

    const int jj = tid & 63, bg = tid >> 6;
    const int j = jt * 64 + jj, b = bt * 4 + bg;
    const float* Arow = A + (size_t)j * 512;
    float acc0 = abias[j], acc1 = 0.f;
    for (int k = 0; k < 512; k += 8) {
        f32x4 a0 = *(const f32x4*)(Arow + k);
        f32x4 a1 = *(const f32x4*)(Arow + k + 4);
        f32x4 c0 = *(const f32x4*)&conc[bg][k];
        f32x4 c1 = *(const f32x4*)&conc[bg][k + 4];
#pragma unroll
        for (int u = 0; u < 4; ++u) {
            acc0 = fmaf(a0[u], c0[u], acc0);
            acc1 = fmaf(a1[u], c1[u], acc1);
        }
    }
    out[(size_t)b * MLPN + j] = fmaxf(acc0 + acc1, 0.f);
}

// ---------------------------------------------------------------------------
extern "C" void kernel_launch(void* const* d_in, const int* in_sizes, int n_in,
                              void* d_out, int out_size, void* d_ws, size_t ws_size,
                              hipStream_t stream) {
    const int*   sent1 = (const int*)d_in[0];
    const int*   ops1  = (const int*)d_in[1];
    const int*   oopl1 = (const int*)d_in[2];
    const int*   sent2 = (const int*)d_in[3];
    const int*   ops2  = (const int*)d_in[4];
    const int*   oopl2 = (const int*)d_in[5];
    const float* W     = (const float*)d_in[6];
    const float* U     = (const float*)d_in[7];
    const float* bias  = (const float*)d_in[8];
    const float* eu    = (const float*)d_in[9];
    const float* unk   = (const float*)d_in[10];
    const float* wemb  = (const float*)d_in[11];
    const float* A     = (const float*)d_in[12];
    const float* ab    = (const float*)d_in[13];
    const float* invt  = (const float*)d_in[14];
    float* out = (float*)d_out;
    (void)in_sizes; (void)n_in; (void)out_size; (void)ws_size;

    char* ws = (char*)d_ws;
    // ws layout (bytes):
    const size_t CHART_OFF = 0;                  // 2*64*127*256*4 = 16,646,144
    const size_t WTB_OFF   = 16646144;           // 204800*2       =    409,600
    const size_t UTB_OFF   = 17055744;           // 163840*2       =    327,680
    const size_t LIST_OFF  = 17383424;           // 256
    const size_t NB_OFF    = 17383680;           // 256 (nlive + barrier counter)
    const size_t ESCR_OFF  = 17383936;           // 128*4*32*2*4   =    131,072
    float* chart     = (float*)(ws + CHART_OFF);
    short* WTB       = (short*)(ws + WTB_OFF);
    short* UTB       = (short*)(ws + UTB_OFF);
    int*   live_list = (int*)(ws + LIST_OFF);
    int*   nlive_bar = (int*)(ws + NB_OFF);
    float* e_scr     = (float*)(ws + ESCR_OFF);

    // prep: (PW+PU+PZ)/256 = 684 work blocks + 1 liveness block
    prep_kernel<<<685, 256, 0, stream>>>(W, U, ops1, ops2, oopl1, oopl2,
                                         WTB, UTB, chart, live_list, nlive_bar);

    leaf_kernel<<<256, 256, 0, stream>>>(sent1, sent2, WTB, bias, unk, wemb, chart);

    step_kernel<<<GRID_STEP, 256, 0, stream>>>(ops1, ops2, UTB, bias, eu, invt, chart,
                                               live_list, nlive_bar, e_scr);

    mlp_kernel<<<256, 256, 0, stream>>>(chart, oopl1, oopl2, A, ab, out);
}

// Round 4
// 188.575 us; speedup vs baseline: 1.8712x; 1.1351x over previous
//
#include <hip/hip_runtime.h>
#include <hip/hip_bf16.h>

// Problem constants
#define BSZ 64
#define LL  64
#define SS  63
#define AMB 32
#define HH  128
#define EE  300
#define MLPN 1024
#define GG  640      // 5*H
#define K2  256      // 2*H
#define PP  127      // L+S

typedef __attribute__((ext_vector_type(8))) short short8;   // 8 bf16 MFMA A/B frag
typedef __attribute__((ext_vector_type(4))) float f32x4;

__device__ __forceinline__ float sigf(float x) { return 1.f / (1.f + __expf(-x)); }

__device__ __forceinline__ unsigned short f2bf(float x) {
    unsigned int u = __float_as_uint(x);
    u += 0x7fffu + ((u >> 16) & 1u);      // RNE
    return (unsigned short)(u >> 16);
}

// ---------------------------------------------------------------------------
// Prep: pack W -> WTB, U -> UTB as bf16 B-operand fragments of
// mfma_f32_16x16x32_bf16:
//   XTB[((n*KSTEPS + kk)*64 + lane)*8 + j] = X[g][k],
//   g = n*16 + (lane&15), k = kk*32 + (lane>>4)*8 + j
// ---------------------------------------------------------------------------
#define PW 25600     // WTB short8 items: 40 ntiles * 10 ksteps * 64 lanes
#define PU 20480     // UTB short8 items: 40 * 8 * 64
__global__ void __launch_bounds__(256) prep_kernel(
        const float* __restrict__ W, const float* __restrict__ U,
        short* __restrict__ WTB, short* __restrict__ UTB) {
    int idx = blockIdx.x * 256 + threadIdx.x;
    if (idx < PW) {
        int lane = idx & 63, r = idx >> 6;
        int kk = r % 10, n = r / 10;
        int g = n * 16 + (lane & 15);
        int k0 = kk * 32 + ((lane >> 4) << 3);
        const float* src = W + (size_t)g * EE + k0;
        float f[8];
        if (k0 + 8 <= EE) {
            f32x4 x0 = *(const f32x4*)src;
            f32x4 x1 = *(const f32x4*)(src + 4);
            f[0]=x0[0]; f[1]=x0[1]; f[2]=x0[2]; f[3]=x0[3];
            f[4]=x1[0]; f[5]=x1[1]; f[6]=x1[2]; f[7]=x1[3];
        } else {
#pragma unroll
            for (int j = 0; j < 8; ++j) f[j] = (k0 + j < EE) ? src[j] : 0.f;
        }
        short8 v;
#pragma unroll
        for (int j = 0; j < 8; ++j) v[j] = (short)f2bf(f[j]);
        *(short8*)(WTB + (size_t)idx * 8) = v;
    } else if (idx < PW + PU) {
        int o = idx - PW;
        int lane = o & 63, r = o >> 6;
        int kk = r & 7, n = r >> 3;
        int g = n * 16 + (lane & 15);
        int k0 = kk * 32 + ((lane >> 4) << 3);
        const float* src = U + (size_t)g * K2 + k0;
        f32x4 x0 = *(const f32x4*)src;
        f32x4 x1 = *(const f32x4*)(src + 4);
        short8 v;
        v[0]=(short)f2bf(x0[0]); v[1]=(short)f2bf(x0[1]); v[2]=(short)f2bf(x0[2]); v[3]=(short)f2bf(x0[3]);
        v[4]=(short)f2bf(x1[0]); v[5]=(short)f2bf(x1[1]); v[6]=(short)f2bf(x1[2]); v[7]=(short)f2bf(x1[3]);
        *(short8*)(UTB + (size_t)o * 8) = v;
    }
}

// ---------------------------------------------------------------------------
// Main fused kernel: 128 blocks (one per (chart,batch) pair) x 1024 threads.
// Phase A: per-batch liveness closure (64-lane ballot mask, register-only).
// Phase B: leaf MFMA GEMM (64 tokens x gates i,o,u) + zero step rows.
// Phase C: live steps, all sync via __syncthreads (no cross-block deps).
// ---------------------------------------------------------------------------
__global__ void __launch_bounds__(1024) main_kernel(
        const int* __restrict__ sent1, const int* __restrict__ sent2,
        const int* __restrict__ ops1, const int* __restrict__ ops2,
        const int* __restrict__ oopl1, const int* __restrict__ oopl2,
        const short* __restrict__ WTB, const short* __restrict__ UTB,
        const float* __restrict__ bias, const float* __restrict__ eu,
        const float* __restrict__ invt,
        const float* __restrict__ unk, const float* __restrict__ wemb,
        float* __restrict__ chart) {
    __shared__ short8 As[40 * 64];          // 40 KiB: leaf 4mt x 10kk; step 2mt x 8kk
    __shared__ float chh[32][132];          // candidate h (16.9 KiB)
    __shared__ float comb[2][2][HH];        // [mt][c|h][col]
    __shared__ int ops_lds[64];
    __shared__ float e_num[AMB], h2s[AMB], s_w[AMB];
    __shared__ int live_list[SS];
    __shared__ int nl_sh;
    __shared__ float un_sh;

    const int tid = threadIdx.x;
    const int pair = blockIdx.x;
    const int ch = pair >> 6, b = pair & 63;
    const int* sent = ch ? sent2 : sent1;
    const int* ops  = ch ? ops2 : ops1;
    const int* oopl = ch ? oopl2 : oopl1;
    float* chbase = chart + (size_t)pair * PP * K2;
    const float it = invt[0];
    const int w = tid >> 6, lane = tid & 63, quad = lane >> 4, l15 = lane & 15;

    // ---- Phase A: liveness (wave 0 only, register ballot mask) ----
    if (tid < 64) {
        float v = eu[tid] * eu[tid] + eu[tid + 64] * eu[tid + 64];
        for (int off = 32; off >= 1; off >>= 1) v += __shfl_xor(v, off);
        if (tid == 0) un_sh = fmaxf(sqrtf(v), 1e-8f);

        unsigned long long mask = 0ull;
        int q0 = oopl[b] - 1 - LL;
        if (q0 >= 0) { if (q0 > SS - 1) q0 = SS - 1; mask = 1ull << q0; }
        for (int t = SS - 1; t >= 1; --t) {
            if (mask & (1ull << t)) {
                int p = ops[(b * SS + t) * 64 + tid];
                int q = p - LL;
                unsigned long long bit = (q >= 0 && q < t) ? (1ull << q) : 0ull;
                for (int off = 32; off >= 1; off >>= 1) bit |= __shfl_xor(bit, off);
                mask |= bit;
            }
        }
        if (tid == 0) {
            int n = 0;
            for (int t = 0; t < SS; ++t)
                if (mask & (1ull << t)) live_list[n++] = t;
            nl_sh = n;
        }
    }

    // ---- Phase B: leaf. Gather embeddings -> A-frags (bf16) ----
#pragma unroll
    for (int i = 0; i < 3; ++i) {
        int slot = i * 1024 + tid;            // 2560 = 64 tok x 40 k-octets
        if (slot < 2560) {
            int t = slot / 40, oct = slot - t * 40;
            int s = sent[b * LL + t];
            const float* src = (s >= 0) ? (wemb + (size_t)s * EE) : unk;
            int k0 = oct * 8;
            float f[8];
            if (k0 + 8 <= EE) {
                f32x4 x0 = *(const f32x4*)(src + k0);
                f32x4 x1 = *(const f32x4*)(src + k0 + 4);
                f[0]=x0[0]; f[1]=x0[1]; f[2]=x0[2]; f[3]=x0[3];
                f[4]=x1[0]; f[5]=x1[1]; f[6]=x1[2]; f[7]=x1[3];
            } else {
#pragma unroll
                for (int j = 0; j < 8; ++j) f[j] = (k0 + j < EE) ? src[k0 + j] : 0.f;
            }
            short8 v;
#pragma unroll
            for (int j = 0; j < 8; ++j) v[j] = (short)f2bf(f[j]);
            As[((t >> 4) * 10 + (oct >> 2)) * 64 + ((oct & 3) << 4) + (t & 15)] = v;
        }
    }
    // zero this pair's step rows (exact reference semantics for fwd refs)
#pragma unroll
    for (int i = 0; i < 4; ++i) {
        int off = i * 4096 + tid * 4;
        if (off < SS * K2) {
            f32x4 z = {0.f, 0.f, 0.f, 0.f};
            *(f32x4*)(chbase + (size_t)LL * K2 + off) = z;
        }
    }
    __syncthreads();

    // leaf GEMM: 16 waves = 4 Mtiles x 4 nu-groups; each wave 2 nus x 3 gates
    {
        const int mt = w & 3, nug = w >> 2;
        f32x4 acc[2][3] = {};
        for (int kk = 0; kk < 10; ++kk) {
            short8 a0 = As[(mt * 10 + kk) * 64 + lane];
#pragma unroll
            for (int si = 0; si < 3; ++si) {
                int s5 = (si == 0) ? 0 : (si == 1 ? 3 : 4);   // gates i,o,u
#pragma unroll
                for (int hf = 0; hf < 2; ++hf) {
                    int n = (nug + hf * 4) + 8 * s5;
                    short8 bv = *(const short8*)(WTB + ((size_t)(n * 10 + kk) * 64 + lane) * 8);
                    acc[hf][si] = __builtin_amdgcn_mfma_f32_16x16x32_bf16(a0, bv, acc[hf][si], 0, 0, 0);
                }
            }
        }
#pragma unroll
        for (int hf = 0; hf < 2; ++hf) {
            int jc = (nug + hf * 4) * 16 + l15;
            float bi = bias[jc], bo = bias[3 * HH + jc], bu = bias[4 * HH + jc];
#pragma unroll
            for (int r = 0; r < 4; ++r) {
                float pi = acc[hf][0][r] + bi;
                float po = acc[hf][1][r] + bo;
                float pu = acc[hf][2][r] + bu;
                float cv = sigf(pi) * tanhf(pu);
                float hv = sigf(po) * tanhf(cv);
                int l = mt * 16 + quad * 4 + r;
                chbase[(size_t)l * K2 + jc]      = cv;
                chbase[(size_t)l * K2 + HH + jc] = hv;
            }
        }
    }
    __syncthreads();

    // ---- Phase C: live steps ----
    const int nl = nl_sh;
    const float eul = eu[lane], euh = eu[64 + lane];
    const int smt = w & 1, snu = w >> 1;          // step GEMM: 2 mt x 8 nu
    const int sjc = snu * 16 + l15;
    const float bi  = bias[sjc],          bfl = bias[HH + sjc];
    const float bfr = bias[2 * HH + sjc], bo  = bias[3 * HH + sjc];
    const float bu  = bias[4 * HH + sjc];

    for (int sidx = 0; sidx < nl; ++sidx) {
        const int t = live_list[sidx];
        if (tid < 64) ops_lds[tid] = min(max(ops[(b * SS + t) * 64 + tid], 0), PP - 1);
        __syncthreads();

        // gather h -> bf16 A-frags (1024 slots = 32 cand x 32 octets)
        {
            int a = tid >> 5, oct = tid & 31, side = oct >> 4, m8 = oct & 15;
            const float* src = chbase + (size_t)ops_lds[2 * a + side] * K2 + HH + m8 * 8;
            f32x4 x0 = *(const f32x4*)src;
            f32x4 x1 = *(const f32x4*)(src + 4);
            short8 v;
            v[0]=(short)f2bf(x0[0]); v[1]=(short)f2bf(x0[1]); v[2]=(short)f2bf(x0[2]); v[3]=(short)f2bf(x0[3]);
            v[4]=(short)f2bf(x1[0]); v[5]=(short)f2bf(x1[1]); v[6]=(short)f2bf(x1[2]); v[7]=(short)f2bf(x1[3]);
            As[((a >> 4) * 8 + (oct >> 2)) * 64 + ((oct & 3) << 4) + (a & 15)] = v;
        }
        __syncthreads();

        // GEMM + gates (ccL/ccR direct from L2-hot chart)
        float cvals[4], hvals[4];
        {
            f32x4 acc[5] = {};
            for (int kk = 0; kk < 8; ++kk) {
                short8 a0 = As[(smt * 8 + kk) * 64 + lane];
#pragma unroll
                for (int s5 = 0; s5 < 5; ++s5) {
                    short8 bv = *(const short8*)(UTB + ((size_t)((snu + 8 * s5) * 8 + kk) * 64 + lane) * 8);
                    acc[s5] = __builtin_amdgcn_mfma_f32_16x16x32_bf16(a0, bv, acc[s5], 0, 0, 0);
                }
            }
#pragma unroll
            for (int r = 0; r < 4; ++r) {
                int a = smt * 16 + quad * 4 + r;
                float ccLv = chbase[(size_t)ops_lds[2 * a] * K2 + sjc];
                float ccRv = chbase[(size_t)ops_lds[2 * a + 1] * K2 + sjc];
                float cv = sigf(acc[1][r] + bfl) * ccLv
                         + sigf(acc[2][r] + bfr) * ccRv
                         + sigf(acc[0][r] + bi) * tanhf(acc[4][r] + bu);
                float hv = sigf(acc[3][r] + bo) * tanhf(cv);
                cvals[r] = cv; hvals[r] = hv;
                chh[a][sjc] = hv;
            }
        }
        __syncthreads();

        // energy per candidate (16 waves x 2 cands)
#pragma unroll
        for (int i = 0; i < 2; ++i) {
            int a = w * 2 + i;
            float h0 = chh[a][lane], h1 = chh[a][64 + lane];
            float pe = h0 * eul + h1 * euh;
            float pn = h0 * h0 + h1 * h1;
            for (int off = 32; off >= 1; off >>= 1) {
                pe += __shfl_xor(pe, off);
                pn += __shfl_xor(pn, off);
            }
            if (lane == 0) { e_num[a] = pe; h2s[a] = pn; }
        }
        __syncthreads();

        // softmax over 32 candidates (wave 0)
        if (tid < 64) {
            float v = (tid < AMB)
                ? (e_num[tid] / (fmaxf(sqrtf(h2s[tid]), 1e-8f) * un_sh)) * it
                : -3.4e38f;
            float m = v;
            for (int off = 32; off >= 1; off >>= 1) m = fmaxf(m, __shfl_xor(m, off));
            float ex = (tid < AMB) ? __expf(v - m) : 0.f;
            float su = ex;
            for (int off = 32; off >= 1; off >>= 1) su += __shfl_xor(su, off);
            if (tid < AMB) s_w[tid] = ex / su;
        }
        __syncthreads();

        // combine: per-wave weighted sums from registers, reduce across quads
        {
            float sc = 0.f, sh = 0.f;
#pragma unroll
            for (int r = 0; r < 4; ++r) {
                int a = smt * 16 + quad * 4 + r;
                float sw = s_w[a];
                sc = fmaf(sw, cvals[r], sc);
                sh = fmaf(sw, hvals[r], sh);
            }
            sc += __shfl_xor(sc, 16); sc += __shfl_xor(sc, 32);
            sh += __shfl_xor(sh, 16); sh += __shfl_xor(sh, 32);
            if (lane < 16) {
                comb[smt][0][sjc] = sc;
                comb[smt][1][sjc] = sh;
            }
        }
        __syncthreads();
        if (tid < K2) {
            int part = tid >> 7, col = tid & 127;
            float val = comb[0][part][col] + comb[1][part][col];
            chbase[(size_t)(LL + t) * K2 + part * HH + col] = val;
        }
        __syncthreads();
    }
}

// ---------------------------------------------------------------------------
// MLP readout: 256 blocks = 16 j-tiles x 16 b-tiles (4 batch rows each).
// ---------------------------------------------------------------------------
__global__ void __launch_bounds__(256) mlp_kernel(
        const float* __restrict__ chart,
        const int* __restrict__ oopl1, const int* __restrict__ oopl2,
        const float* __restrict__ A, const float* __restrict__ abias,
        float* __restrict__ out) {
    __shared__ __align__(16) float conc[4][512];
    const int tid = threadIdx.x;
    const int jt = blockIdx.x & 15, bt = blockIdx.x >> 4;

#pragma unroll
    for (int i = 0; i < 2; ++i) {
        int s = i * 256 + tid;                // 512 vec4 slots = 4 b x 128
        int bl = s >> 7, kv = s & 127;
        int k0 = kv * 4, sel = k0 >> 7, kk0 = k0 & 127;
        int b = bt * 4 + bl;
        int p1 = min(max(oopl1[b] - 1, 0), PP - 1);
        int p2 = min(max(oopl2[b] - 1, 0), PP - 1);
        f32x4 s1 = *(const f32x4*)(chart + ((size_t)(b * PP + p1)) * K2 + HH + kk0);
        f32x4 s2 = *(const f32x4*)(chart + ((size_t)((BSZ + b) * PP + p2)) * K2 + HH + kk0);
        f32x4 v;
        if (sel == 0)      { f32x4 d = s1 - s2; v = d * d; }
        else if (sel == 1) v = s1 * s2;
        else if (sel == 2) v = s1;
        else               v = s2;
        *(f32x4*)&conc[bl][k0] = v;
    }
    __syncthreads();

    const int jj = tid & 63, bg = tid >> 6;
    const int j = jt * 64 + jj, b = bt * 4 + bg;
    const float* Arow = A + (size_t)j * 512;
    float acc0 = abias[j], acc1 = 0.f;
    for (int k = 0; k < 512; k += 8) {
        f32x4 a0 = *(const f32x4*)(Arow + k);
        f32x4 a1 = *(const f32x4*)(Arow + k + 4);
        f32x4 c0 = *(const f32x4*)&conc[bg][k];
        f32x4 c1 = *(const f32x4*)&conc[bg][k + 4];
#pragma unroll
        for (int u = 0; u < 4; ++u) {
            acc0 = fmaf(a0[u], c0[u], acc0);
            acc1 = fmaf(a1[u], c1[u], acc1);
        }
    }
    out[(size_t)b * MLPN + j] = fmaxf(acc0 + acc1, 0.f);
}

// ---------------------------------------------------------------------------
extern "C" void kernel_launch(void* const* d_in, const int* in_sizes, int n_in,
                              void* d_out, int out_size, void* d_ws, size_t ws_size,
                              hipStream_t stream) {
    const int*   sent1 = (const int*)d_in[0];
    const int*   ops1  = (const int*)d_in[1];
    const int*   oopl1 = (const int*)d_in[2];
    const int*   sent2 = (const int*)d_in[3];
    const int*   ops2  = (const int*)d_in[4];
    const int*   oopl2 = (const int*)d_in[5];
    const float* W     = (const float*)d_in[6];
    const float* U     = (const float*)d_in[7];
    const float* bias  = (const float*)d_in[8];
    const float* eu    = (const float*)d_in[9];
    const float* unk   = (const float*)d_in[10];
    const float* wemb  = (const float*)d_in[11];
    const float* A     = (const float*)d_in[12];
    const float* ab    = (const float*)d_in[13];
    const float* invt  = (const float*)d_in[14];
    float* out = (float*)d_out;
    (void)in_sizes; (void)n_in; (void)out_size; (void)ws_size;

    char* ws = (char*)d_ws;
    // ws layout (bytes):
    const size_t CHART_OFF = 0;                  // 2*64*127*256*4 = 16,646,144
    const size_t WTB_OFF   = 16646144;           // 204800*2       =    409,600
    const size_t UTB_OFF   = 17055744;           // 163840*2       =    327,680
    float* chart = (float*)(ws + CHART_OFF);
    short* WTB   = (short*)(ws + WTB_OFF);
    short* UTB   = (short*)(ws + UTB_OFF);

    // prep: (PW+PU)/256 = 180 blocks
    prep_kernel<<<180, 256, 0, stream>>>(W, U, WTB, UTB);

    main_kernel<<<128, 1024, 0, stream>>>(sent1, sent2, ops1, ops2, oopl1, oopl2,
                                          WTB, UTB, bias, eu, invt, unk, wemb, chart);

    mlp_kernel<<<256, 256, 0, stream>>>(chart, oopl1, oopl2, A, ab, out);
}

// Round 5
// 186.978 us; speedup vs baseline: 1.8872x; 1.0085x over previous
//
#include <hip/hip_runtime.h>
#include <hip/hip_bf16.h>

// Problem constants
#define BSZ 64
#define LL  64
#define SS  63
#define AMB 32
#define HH  128
#define EE  300
#define MLPN 1024
#define GG  640      // 5*H
#define K2  256      // 2*H
#define PP  127      // L+S
#define CROW 272     // chart LDS row stride in shorts (544 B; 544%128=32 -> bank spread)

typedef __attribute__((ext_vector_type(8))) short short8;   // 8 bf16 MFMA A/B frag
typedef __attribute__((ext_vector_type(4))) float f32x4;

__device__ __forceinline__ float sigf(float x) { return 1.f / (1.f + __expf(-x)); }

__device__ __forceinline__ unsigned short f2bf(float x) {
    unsigned int u = __float_as_uint(x);
    u += 0x7fffu + ((u >> 16) & 1u);      // RNE
    return (unsigned short)(u >> 16);
}
__device__ __forceinline__ float bf2f(short x) {
    return __uint_as_float(((unsigned)(unsigned short)x) << 16);
}

// ---------------------------------------------------------------------------
// Prep: pack W -> WTB, U -> UTB as bf16 B-operand fragments of
// mfma_f32_16x16x32_bf16:
//   XTB[((n*KSTEPS + kk)*64 + lane)*8 + j] = X[g][k],
//   g = n*16 + (lane&15), k = kk*32 + (lane>>4)*8 + j
// ---------------------------------------------------------------------------
#define PW 25600     // WTB short8 items: 40 ntiles * 10 ksteps * 64 lanes
#define PU 20480     // UTB short8 items: 40 * 8 * 64
__global__ void __launch_bounds__(256) prep_kernel(
        const float* __restrict__ W, const float* __restrict__ U,
        short* __restrict__ WTB, short* __restrict__ UTB) {
    int idx = blockIdx.x * 256 + threadIdx.x;
    if (idx < PW) {
        int lane = idx & 63, r = idx >> 6;
        int kk = r % 10, n = r / 10;
        int g = n * 16 + (lane & 15);
        int k0 = kk * 32 + ((lane >> 4) << 3);
        const float* src = W + (size_t)g * EE + k0;
        float f[8];
        if (k0 + 8 <= EE) {
            f32x4 x0 = *(const f32x4*)src;
            f32x4 x1 = *(const f32x4*)(src + 4);
            f[0]=x0[0]; f[1]=x0[1]; f[2]=x0[2]; f[3]=x0[3];
            f[4]=x1[0]; f[5]=x1[1]; f[6]=x1[2]; f[7]=x1[3];
        } else {
#pragma unroll
            for (int j = 0; j < 8; ++j) f[j] = (k0 + j < EE) ? src[j] : 0.f;
        }
        short8 v;
#pragma unroll
        for (int j = 0; j < 8; ++j) v[j] = (short)f2bf(f[j]);
        *(short8*)(WTB + (size_t)idx * 8) = v;
    } else if (idx < PW + PU) {
        int o = idx - PW;
        int lane = o & 63, r = o >> 6;
        int kk = r & 7, n = r >> 3;
        int g = n * 16 + (lane & 15);
        int k0 = kk * 32 + ((lane >> 4) << 3);
        const float* src = U + (size_t)g * K2 + k0;
        f32x4 x0 = *(const f32x4*)src;
        f32x4 x1 = *(const f32x4*)(src + 4);
        short8 v;
        v[0]=(short)f2bf(x0[0]); v[1]=(short)f2bf(x0[1]); v[2]=(short)f2bf(x0[2]); v[3]=(short)f2bf(x0[3]);
        v[4]=(short)f2bf(x1[0]); v[5]=(short)f2bf(x1[1]); v[6]=(short)f2bf(x1[2]); v[7]=(short)f2bf(x1[3]);
        *(short8*)(UTB + (size_t)o * 8) = v;
    }
}

// ---------------------------------------------------------------------------
// Main fused kernel: 128 blocks x 1024 threads; one (chart,batch) pair per
// block. The ENTIRE chart lives in LDS as bf16 (127 x 256, 544 B row stride).
// Liveness: parallel per-step masks + LDS-only serial closure (no dependent
// global loads). Output: only the final readout row (256 f32) per pair.
// ---------------------------------------------------------------------------
__global__ void __launch_bounds__(1024) main_kernel(
        const int* __restrict__ sent1, const int* __restrict__ sent2,
        const int* __restrict__ ops1, const int* __restrict__ ops2,
        const int* __restrict__ oopl1, const int* __restrict__ oopl2,
        const short* __restrict__ WTB, const short* __restrict__ UTB,
        const float* __restrict__ bias, const float* __restrict__ eu,
        const float* __restrict__ invt,
        const float* __restrict__ unk, const float* __restrict__ wemb,
        float* __restrict__ fin) {
    __shared__ __align__(16) short chartL[127 * CROW + 16];   // 69.1 KiB bf16 chart
    __shared__ __align__(16) char  buf[40960];   // leaf A-frags 40K / step A-frags 16K + chh
    __shared__ int ops_all[SS * 64];             // 16.1 KiB (liveness + step gathers)
    __shared__ int sent_lds[64];
    __shared__ unsigned long long smask[64];
    __shared__ int live_list[SS];
    __shared__ float e_num[AMB], h2s[AMB], s_w[AMB];
    __shared__ float comb[2][2][HH];
    __shared__ int nl_sh;
    __shared__ float un_sh;

    short8* AsL = (short8*)buf;                  // leaf: 4 mt x 10 kk x 64
    short8* As2 = (short8*)buf;                  // step: 2 mt x 8 kk x 64
    float*  chh = (float*)(buf + 16384);         // step: 32 x 132 f32

    const int tid = threadIdx.x;
    const int pair = blockIdx.x, ch = pair >> 6, b = pair & 63;
    const int* sent = ch ? sent2 : sent1;
    const int* ops  = ch ? ops2 : ops1;
    const int* oopl = ch ? oopl2 : oopl1;
    const float it = invt[0];
    const int w = tid >> 6, lane = tid & 63, quad = lane >> 4, l15 = lane & 15;

    // ---- A0: cooperative loads (all parallel, no dependent chains) ----
#pragma unroll
    for (int i = 0; i < 4; ++i) {
        int idx = i * 1024 + tid;
        if (idx < SS * 64) ops_all[idx] = min(max(ops[b * SS * 64 + idx], 0), PP - 1);
    }
    if (tid < 64) sent_lds[tid] = sent[b * LL + tid];
    if (tid < 64) {
        float v = eu[tid] * eu[tid] + eu[tid + 64] * eu[tid + 64];
        for (int off = 32; off >= 1; off >>= 1) v += __shfl_xor(v, off);
        if (tid == 0) un_sh = fmaxf(sqrtf(v), 1e-8f);
    }
    __syncthreads();

    // ---- A1: per-step candidate masks (16 waves x up to 4 steps) ----
#pragma unroll
    for (int i = 0; i < 4; ++i) {
        int t = i * 16 + w;
        if (t < SS) {
            int q = ops_all[t * 64 + lane] - LL;
            unsigned long long bit = (q >= 0 && q < t) ? (1ull << q) : 0ull;
            for (int off = 32; off >= 1; off >>= 1) bit |= __shfl_xor(bit, off);
            if (lane == 0) smask[t] = bit;
        }
    }
    __syncthreads();

    // ---- A2: serial closure (LDS-only, ~62 iters) by thread 0 ----
    if (tid == 0) {
        unsigned long long mask = 0ull;
        int q0 = oopl[b] - 1 - LL;
        if (q0 >= 0) { if (q0 > SS - 1) q0 = SS - 1; mask = 1ull << q0; }
        for (int t = SS - 1; t >= 1; --t)
            if ((mask >> t) & 1) mask |= smask[t];
        int n = 0;
        for (int t = 0; t < SS; ++t)
            if ((mask >> t) & 1) live_list[n++] = t;
        nl_sh = n;
    }

    // ---- B: zero step rows; gather embeddings -> leaf A-frags ----
#pragma unroll
    for (int i = 0; i < 3; ++i) {
        int idx = i * 1024 + tid;
        if (idx < 2142)   // 63 rows x 272 shorts = 2142 int4
            ((int4*)(chartL + 64 * CROW))[idx] = make_int4(0, 0, 0, 0);
    }
    {
        float ef[3][8];
        int est[3], eso[3];
#pragma unroll
        for (int i = 0; i < 3; ++i) {
            int slot = i * 1024 + tid;            // 2560 = 64 tok x 40 k-octets
            est[i] = -1;
            if (slot < 2560) {
                int t = slot / 40, oct = slot - t * 40;
                est[i] = t; eso[i] = oct;
                int s = sent_lds[t];
                const float* src = (s >= 0) ? (wemb + (size_t)s * EE) : unk;
                int k0 = oct * 8;
                if (k0 + 8 <= EE) {
                    f32x4 x0 = *(const f32x4*)(src + k0);
                    f32x4 x1 = *(const f32x4*)(src + k0 + 4);
                    ef[i][0]=x0[0]; ef[i][1]=x0[1]; ef[i][2]=x0[2]; ef[i][3]=x0[3];
                    ef[i][4]=x1[0]; ef[i][5]=x1[1]; ef[i][6]=x1[2]; ef[i][7]=x1[3];
                } else {
#pragma unroll
                    for (int j = 0; j < 8; ++j) ef[i][j] = (k0 + j < EE) ? src[k0 + j] : 0.f;
                }
            }
        }
#pragma unroll
        for (int i = 0; i < 3; ++i) {
            if (est[i] >= 0) {
                int t = est[i], oct = eso[i];
                short8 v;
#pragma unroll
                for (int j = 0; j < 8; ++j) v[j] = (short)f2bf(ef[i][j]);
                AsL[((t >> 4) * 10 + (oct >> 2)) * 64 + ((oct & 3) << 4) + (t & 15)] = v;
            }
        }
    }
    __syncthreads();

    // ---- leaf GEMM: 16 waves = 4 Mtiles x 4 nu-groups; gates i,o,u ----
    {
        const int mt = w & 3, nug = w >> 2;
        f32x4 acc[2][3] = {};
        for (int kk = 0; kk < 10; ++kk) {
            short8 a0 = AsL[(mt * 10 + kk) * 64 + lane];
#pragma unroll
            for (int si = 0; si < 3; ++si) {
                int s5 = (si == 0) ? 0 : (si == 1 ? 3 : 4);
#pragma unroll
                for (int hf = 0; hf < 2; ++hf) {
                    int n = (nug + hf * 4) + 8 * s5;
                    short8 bv = *(const short8*)(WTB + ((size_t)(n * 10 + kk) * 64 + lane) * 8);
                    acc[hf][si] = __builtin_amdgcn_mfma_f32_16x16x32_bf16(a0, bv, acc[hf][si], 0, 0, 0);
                }
            }
        }
#pragma unroll
        for (int hf = 0; hf < 2; ++hf) {
            int jc = (nug + hf * 4) * 16 + l15;
            float bi = bias[jc], bo = bias[3 * HH + jc], bu = bias[4 * HH + jc];
#pragma unroll
            for (int r = 0; r < 4; ++r) {
                float pi = acc[hf][0][r] + bi;
                float po = acc[hf][1][r] + bo;
                float pu = acc[hf][2][r] + bu;
                float cv = sigf(pi) * tanhf(pu);
                float hv = sigf(po) * tanhf(cv);
                int l = mt * 16 + quad * 4 + r;
                chartL[l * CROW + jc]      = (short)f2bf(cv);
                chartL[l * CROW + HH + jc] = (short)f2bf(hv);
            }
        }
    }
    __syncthreads();

    // ---- C: live steps (all LDS) ----
    const int nl = nl_sh;
    const float eul = eu[lane], euh = eu[64 + lane];
    const int smt = w & 1, snu = w >> 1;
    const int sjc = snu * 16 + l15;
    const float bi  = bias[sjc],          bfl = bias[HH + sjc];
    const float bfr = bias[2 * HH + sjc], bo  = bias[3 * HH + sjc];
    const float bu  = bias[4 * HH + sjc];

    for (int sidx = 0; sidx < nl; ++sidx) {
        const int t = live_list[sidx];
        const int* oprow = ops_all + t * 64;

        // gather h -> step A-frags (pure LDS->LDS b128, no conversion)
        {
            int a = tid >> 5, oct = tid & 31, side = oct >> 4, m8 = oct & 15;
            int row = oprow[2 * a + side];
            short8 v = *(const short8*)(chartL + row * CROW + HH + m8 * 8);
            As2[((a >> 4) * 8 + (oct >> 2)) * 64 + ((oct & 3) << 4) + (a & 15)] = v;
        }
        __syncthreads();

        float cvals[4], hvals[4];
        {
            f32x4 acc[5] = {};
            for (int kk = 0; kk < 8; ++kk) {
                short8 a0 = As2[(smt * 8 + kk) * 64 + lane];
#pragma unroll
                for (int s5 = 0; s5 < 5; ++s5) {
                    short8 bv = *(const short8*)(UTB + ((size_t)((snu + 8 * s5) * 8 + kk) * 64 + lane) * 8);
                    acc[s5] = __builtin_amdgcn_mfma_f32_16x16x32_bf16(a0, bv, acc[s5], 0, 0, 0);
                }
            }
#pragma unroll
            for (int r = 0; r < 4; ++r) {
                int a = smt * 16 + quad * 4 + r;
                float ccLv = bf2f(chartL[oprow[2 * a] * CROW + sjc]);
                float ccRv = bf2f(chartL[oprow[2 * a + 1] * CROW + sjc]);
                float cv = sigf(acc[1][r] + bfl) * ccLv
                         + sigf(acc[2][r] + bfr) * ccRv
                         + sigf(acc[0][r] + bi) * tanhf(acc[4][r] + bu);
                float hv = sigf(acc[3][r] + bo) * tanhf(cv);
                cvals[r] = cv; hvals[r] = hv;
                chh[a * 132 + sjc] = hv;
            }
        }
        __syncthreads();

        // energy per candidate (16 waves x 2 cands)
#pragma unroll
        for (int i = 0; i < 2; ++i) {
            int a = w * 2 + i;
            float h0 = chh[a * 132 + lane], h1 = chh[a * 132 + 64 + lane];
            float pe = h0 * eul + h1 * euh;
            float pn = h0 * h0 + h1 * h1;
            for (int off = 32; off >= 1; off >>= 1) {
                pe += __shfl_xor(pe, off);
                pn += __shfl_xor(pn, off);
            }
            if (lane == 0) { e_num[a] = pe; h2s[a] = pn; }
        }
        __syncthreads();

        // softmax over 32 candidates (wave 0)
        if (tid < 64) {
            float v = (tid < AMB)
                ? (e_num[tid] / (fmaxf(sqrtf(h2s[tid]), 1e-8f) * un_sh)) * it
                : -3.4e38f;
            float m = v;
            for (int off = 32; off >= 1; off >>= 1) m = fmaxf(m, __shfl_xor(m, off));
            float ex = (tid < AMB) ? __expf(v - m) : 0.f;
            float su = ex;
            for (int off = 32; off >= 1; off >>= 1) su += __shfl_xor(su, off);
            if (tid < AMB) s_w[tid] = ex / su;
        }
        __syncthreads();

        // combine from registers, reduce across quads, write chart row L+t
        {
            float sc = 0.f, sh = 0.f;
#pragma unroll
            for (int r = 0; r < 4; ++r) {
                int a = smt * 16 + quad * 4 + r;
                float sw = s_w[a];
                sc = fmaf(sw, cvals[r], sc);
                sh = fmaf(sw, hvals[r], sh);
            }
            sc += __shfl_xor(sc, 16); sc += __shfl_xor(sc, 32);
            sh += __shfl_xor(sh, 16); sh += __shfl_xor(sh, 32);
            if (lane < 16) {
                comb[smt][0][sjc] = sc;
                comb[smt][1][sjc] = sh;
            }
        }
        __syncthreads();
        if (tid < K2) {
            int part = tid >> 7, col = tid & 127;
            float val = comb[0][part][col] + comb[1][part][col];
            chartL[(LL + t) * CROW + part * HH + col] = (short)f2bf(val);
        }
        __syncthreads();
    }

    // ---- final readout row -> global ----
    int p = min(max(oopl[b] - 1, 0), PP - 1);
    if (tid < K2)
        fin[(size_t)pair * K2 + tid] = bf2f(chartL[p * CROW + tid]);
}

// ---------------------------------------------------------------------------
// MLP readout: 256 blocks = 16 j-tiles x 16 b-tiles (4 batch rows each).
// ---------------------------------------------------------------------------
__global__ void __launch_bounds__(256) mlp_kernel(
        const float* __restrict__ fin,
        const float* __restrict__ A, const float* __restrict__ abias,
        float* __restrict__ out) {
    __shared__ __align__(16) float conc[4][512];
    const int tid = threadIdx.x;
    const int jt = blockIdx.x & 15, bt = blockIdx.x >> 4;

#pragma unroll
    for (int i = 0; i < 2; ++i) {
        int s = i * 256 + tid;                // 512 vec4 slots = 4 b x 128
        int bl = s >> 7, kv = s & 127;
        int k0 = kv * 4, sel = k0 >> 7, kk0 = k0 & 127;
        int b = bt * 4 + bl;
        f32x4 s1 = *(const f32x4*)(fin + (size_t)b * K2 + HH + kk0);
        f32x4 s2 = *(const f32x4*)(fin + (size_t)(BSZ + b) * K2 + HH + kk0);
        f32x4 v;
        if (sel == 0)      { f32x4 d = s1 - s2; v = d * d; }
        else if (sel == 1) v = s1 * s2;
        else if (sel == 2) v = s1;
        else               v = s2;
        *(f32x4*)&conc[bl][k0] = v;
    }
    __syncthreads();

    const int jj = tid & 63, bg = tid >> 6;
    const int j = jt * 64 + jj, b = bt * 4 + bg;
    const float* Arow = A + (size_t)j * 512;
    float acc0 = abias[j], acc1 = 0.f;
    for (int k = 0; k < 512; k += 8) {
        f32x4 a0 = *(const f32x4*)(Arow + k);
        f32x4 a1 = *(const f32x4*)(Arow + k + 4);
        f32x4 c0 = *(const f32x4*)&conc[bg][k];
        f32x4 c1 = *(const f32x4*)&conc[bg][k + 4];
#pragma unroll
        for (int u = 0; u < 4; ++u) {
            acc0 = fmaf(a0[u], c0[u], acc0);
            acc1 = fmaf(a1[u], c1[u], acc1);
        }
    }
    out[(size_t)b * MLPN + j] = fmaxf(acc0 + acc1, 0.f);
}

// ---------------------------------------------------------------------------
extern "C" void kernel_launch(void* const* d_in, const int* in_sizes, int n_in,
                              void* d_out, int out_size, void* d_ws, size_t ws_size,
                              hipStream_t stream) {
    const int*   sent1 = (const int*)d_in[0];
    const int*   ops1  = (const int*)d_in[1];
    const int*   oopl1 = (const int*)d_in[2];
    const int*   sent2 = (const int*)d_in[3];
    const int*   ops2  = (const int*)d_in[4];
    const int*   oopl2 = (const int*)d_in[5];
    const float* W     = (const float*)d_in[6];
    const float* U     = (const float*)d_in[7];
    const float* bias  = (const float*)d_in[8];
    const float* eu    = (const float*)d_in[9];
    const float* unk   = (const float*)d_in[10];
    const float* wemb  = (const float*)d_in[11];
    const float* A     = (const float*)d_in[12];
    const float* ab    = (const float*)d_in[13];
    const float* invt  = (const float*)d_in[14];
    float* out = (float*)d_out;
    (void)in_sizes; (void)n_in; (void)out_size; (void)ws_size;

    char* ws = (char*)d_ws;
    // ws layout (bytes):
    const size_t WTB_OFF = 0;          // 204800*2 = 409,600
    const size_t UTB_OFF = 409600;     // 163840*2 = 327,680
    const size_t FIN_OFF = 737280;     // 128*256*4 = 131,072
    short* WTB = (short*)(ws + WTB_OFF);
    short* UTB = (short*)(ws + UTB_OFF);
    float* fin = (float*)(ws + FIN_OFF);

    // prep: (PW+PU)/256 = 180 blocks
    prep_kernel<<<180, 256, 0, stream>>>(W, U, WTB, UTB);

    main_kernel<<<128, 1024, 0, stream>>>(sent1, sent2, ops1, ops2, oopl1, oopl2,
                                          WTB, UTB, bias, eu, invt, unk, wemb, fin);

    mlp_kernel<<<256, 256, 0, stream>>>(fin, A, ab, out);
}